// Round 5
// baseline (351.974 us; speedup 1.0000x reference)
//
#include <hip/hip_runtime.h>
#include <math.h>

#define EPSV 1e-5f
#define B 8
#define C 1024
#define C2 512
#define RK 73
#define HW 784      // 28*28
#define QW 3136     // 56*56

typedef __attribute__((ext_vector_type(8))) short bf16x8;
typedef __attribute__((ext_vector_type(4))) float f32x4;

__device__ __forceinline__ unsigned short f2bf(float f) {
    unsigned u = __float_as_uint(f);
    return (unsigned short)((u + 0x7fffu + ((u >> 16) & 1u)) >> 16);
}
__device__ __forceinline__ float ld_f(const float* p) { return *p; }
__device__ __forceinline__ float ld_f(const unsigned short* p) {
    return __uint_as_float(((unsigned)*p) << 16);
}

// ---------- kernel 1: global average pool over y -> s0 ----------
__global__ void gap_kernel(const float* __restrict__ y, float* __restrict__ s0) {
    int bc = blockIdx.x;
    const float* p = y + (size_t)bc * QW;
    float sum = 0.f;
    for (int i = threadIdx.x; i < QW; i += 256) sum += p[i];
    for (int off = 32; off > 0; off >>= 1) sum += __shfl_down(sum, off, 64);
    __shared__ float red[4];
    if ((threadIdx.x & 63) == 0) red[threadIdx.x >> 6] = sum;
    __syncthreads();
    if (threadIdx.x == 0)
        s0[bc] = (red[0] + red[1] + red[2] + red[3]) * (1.0f / QW);
}

// ---------- kernel 2: SE FC layers ----------
__global__ void se_fc_kernel(const float* __restrict__ s0,
                             const float* __restrict__ fc1_w,
                             const float* __restrict__ fc2_w,
                             float* __restrict__ att) {
    int b = blockIdx.x;
    __shared__ float sv[C2];
    __shared__ float hv[RK];
    for (int i = threadIdx.x; i < C2; i += 256) sv[i] = s0[b * C2 + i];
    __syncthreads();
    if (threadIdx.x < RK) {
        float acc = 0.f;
        const float* wr = fc1_w + threadIdx.x * C2;
        for (int k = 0; k < C2; ++k) acc += wr[k] * sv[k];
        hv[threadIdx.x] = fmaxf(acc, 0.f);
    }
    __syncthreads();
    for (int o = threadIdx.x; o < C2; o += 256) {
        float acc = 0.f;
        const float* wr = fc2_w + o * RK;
        for (int j = 0; j < RK; ++j) acc += wr[j] * hv[j];
        att[b * C2 + o] = 1.f / (1.f + expf(-acc));
    }
}

// ---------- kernel 3: depthwise 3x3 conv + row-centered cov -> bf16 ----------
__global__ void dwcov_kernel(const float* __restrict__ x,
                             const float* __restrict__ dw_w,
                             const float* __restrict__ dw_b,
                             unsigned short* __restrict__ cov) {
    int bc = blockIdx.x;
    int c = bc & (C - 1);
    __shared__ float xs[HW];
    __shared__ float x1[HW];
    __shared__ float rm[28];
    const float* px = x + (size_t)bc * HW;
    for (int i = threadIdx.x; i < HW; i += 256) xs[i] = px[i];
    float wk[9];
#pragma unroll
    for (int j = 0; j < 9; ++j) wk[j] = dw_w[c * 9 + j];
    float bias = dw_b[c];
    __syncthreads();
    for (int p = threadIdx.x; p < HW; p += 256) {
        int h = p / 28, w = p - h * 28;
        float acc = bias;
#pragma unroll
        for (int dh = 0; dh < 3; ++dh) {
            int hh = h + dh - 1;
            if (hh < 0 || hh >= 28) continue;
#pragma unroll
            for (int dw = 0; dw < 3; ++dw) {
                int ww = w + dw - 1;
                if (ww < 0 || ww >= 28) continue;
                acc += xs[hh * 28 + ww] * wk[dh * 3 + dw];
            }
        }
        x1[p] = acc;
    }
    __syncthreads();
    if (threadIdx.x < 28) {
        float s = 0.f;
        for (int w = 0; w < 28; ++w) s += x1[threadIdx.x * 28 + w];
        rm[threadIdx.x] = s * (1.f / 28.f);
    }
    __syncthreads();
    unsigned short* pc = cov + (size_t)bc * HW;
    for (int p = threadIdx.x; p < HW; p += 256) {
        int h = p / 28, g = p - h * 28;
        float mh = rm[h], mg = rm[g];
        float acc = 0.f;
        for (int w = 0; w < 28; ++w)
            acc += (x1[h * 28 + w] - mh) * (x1[g * 28 + w] - mg);
        pc[p] = f2bf(acc * (1.f / 27.f));
    }
}

// ---------- pack weights bf16; fold bias+bn scales ----------
__global__ void pack_w(const float* __restrict__ conv_w, const float* __restrict__ conv_b,
                       const float* __restrict__ conv1_w, const float* __restrict__ conv1_b,
                       const float* __restrict__ bn_g, const float* __restrict__ bn_b,
                       const float* __restrict__ bn_m, const float* __restrict__ bn_v,
                       unsigned short* __restrict__ w0b, unsigned short* __restrict__ w1p0,
                       unsigned short* __restrict__ w1pT,
                       float* __restrict__ sA, float* __restrict__ sB0, float* __restrict__ sB1) {
    int o = blockIdx.x, t = threadIdx.x;
    for (int i = t; i < C; i += 256) w0b[(size_t)o * C + i] = f2bf(conv_w[(size_t)o * C + i]);
    for (int i = t; i < C2; i += 256) w1p0[(size_t)o * C2 + i] = f2bf(conv1_w[(size_t)o * 2048 + i]);
    for (int i = t; i < 1536; i += 256) w1pT[(size_t)o * 1536 + i] = f2bf(conv1_w[(size_t)o * 2048 + 512 + i]);
    if (t == 0) {
        float sc = rsqrtf(bn_v[o] + EPSV) * bn_g[o];
        float bi = bn_b[o] - bn_m[o] * sc;
        sA[o] = sc;
        sB0[o] = conv_b[o] * sc + bi;
        sB1[o] = conv1_b[o] * sc + bi;
    }
}

// ---------- tiled transpose+convert: src[b][rows][cols] -> dst[(b,col)][dpitch]+doff ----------
// ATT: multiply row (channel) c by att[b*rows+c] before bf16 rounding (folds SE scale).
template<typename ST, bool ATT>
__global__ __launch_bounds__(256)
void transpose_pass(const ST* __restrict__ src, unsigned short* __restrict__ dst,
                    const float* __restrict__ att,
                    int rows, int cols, int dpitch, int doff) {
    int b = blockIdx.z;
    int c0 = blockIdx.y * 64, p0 = blockIdx.x * 64;
    __shared__ float ts[64][65];
    int tid = threadIdx.x;
    int pl = tid & 63, r0 = tid >> 6;
    const ST* sb = src + ((size_t)b * rows + c0) * cols + p0;
    if (p0 + pl < cols) {
#pragma unroll
        for (int j = 0; j < 16; ++j) {
            int cl = r0 + j * 4;
            ts[cl][pl] = ld_f(&sb[(size_t)cl * cols + pl]);
        }
    }
    __syncthreads();
    int cl = tid & 63;
    float av = ATT ? att[b * rows + c0 + cl] : 1.f;
#pragma unroll
    for (int j = 0; j < 16; ++j) {
        int pl2 = r0 + j * 4;
        if (p0 + pl2 < cols)
            dst[((size_t)b * cols + p0 + pl2) * dpitch + doff + c0 + cl] = f2bf(ts[cl][pl2] * av);
    }
}

// ---------- MFMA GEMM: 128o x 128n block tile, BK=32, XOR-swizzled LDS ----------
// 4 waves (2x2), each owns a 64o x 64n sub-tile -> 16 MFMA per wave per K-step for
// 8 ds_read_b128 (0.5 KB LDS-read per MFMA, half of the old 64x64 tile) and half
// the staging traffic per output element.
// LDS layout: unpadded 64B rows; 16B chunk c of row r stored at r*64 + 16*(c^((r>>1)&3))
// (same XOR on read). Derivation: slot8 = 4*(r&1) + (c^((r>>1)&3)) covers all 8
// bank-slots per 16-lane group, 2 lanes each -> 2-way (free). The old 80B-padded rows
// collapsed onto 8 banks (8-way) -> measured 6.5M conflict cycles/dispatch.
// Pipeline: 2-deep register prefetch; loads stay in flight across raw s_barrier
// (lgkmcnt-only publish, no vmcnt(0) drain per K-step).
// XCD classes balanced & bijective; XCD = bx%8 (grid.x%8==0 keeps this under blockIdx.z).
// MODE 0: A=w0b   K=1024, B=covT  [(b,p)][1024]; epi bn+sigmoid -> BcatT cols 0..511
// MODE 1: A=w1pT  K=1536, B=BcatT [(b,p)][1536]; epi f2bf -> Pb [b][o][784]
// MODE 2: A=w1p0  K=512,  B=yT    [(b,q)][512] (att folded); epi (acc+up(Pb))*bn relu -> out
//         N=3136 -> 25 n-tiles; tile 24 is masked (clamped B rows, guarded stores).
template<int MODE, int K>
__global__ __launch_bounds__(256, 3)
void mfma_gemm(const unsigned short* __restrict__ wpk,
               const unsigned short* __restrict__ bsrc,
               const unsigned short* __restrict__ Pb,
               const float* __restrict__ sA, const float* __restrict__ sB,
               void* __restrict__ outv) {
    constexpr int NIT = K / 32;                  // 16 / 32 / 48
    constexpr int NT  = (MODE == 2) ? 25 : 49;   // n-tiles of 128
    constexpr int QN = NT >> 3, REM = NT & 7;
    int bx = blockIdx.x;
    int r = bx & 7, ii = bx >> 3;
    int og = ii & 3, s = ii >> 2;
    int cnt = QN + (r < REM ? 1 : 0);
    if (s >= cnt) return;
    int t = (r < REM ? r * (QN + 1) : REM * (QN + 1) + (r - REM) * QN) + s;
    int o0 = og * 128;
    int n0 = t * 128;
    int b = blockIdx.z;
    union SM {
        struct { __align__(16) unsigned short Wt[2][4096]; __align__(16) unsigned short At[2][4096]; } s;
        float pt[(MODE == 2) ? 64 * 140 : 4];    // 5-row Pb window per o (two-pass epi)
    };
    __shared__ SM sm;
    int tid = threadIdx.x;
    int lane = tid & 63, wv = tid >> 6;
    int ln = lane & 15, quad = lane >> 4;
    int wr = wv >> 1, wc = wv & 1;               // wave sub-tile: o rows wr*64, n cols wc*64
    // staging: thread covers rows tid>>2 and tid>>2+64, k-chunk tid&3 (8 shorts)
    int srow = tid >> 2, schk = tid & 3;
    int stw = srow * 32 + ((schk ^ ((srow >> 1) & 3)) << 3);   // swizzled write off (shorts)
    int rq  = (quad ^ ((ln >> 1) & 3)) << 3;                   // swizzled read chunk off
    const unsigned short* wg0 = wpk + (size_t)(o0 + srow) * K + schk * 8;
    const unsigned short* wg1 = wg0 + (size_t)64 * K;
    const unsigned short* bg0;
    const unsigned short* bg1;
    if (MODE == 2) {
        int q0 = min(n0 + srow, QW - 1);
        int q1 = min(n0 + srow + 64, QW - 1);
        bg0 = bsrc + ((size_t)b * QW + q0) * K + schk * 8;
        bg1 = bsrc + ((size_t)b * QW + q1) * K + schk * 8;
    } else {
        bg0 = bsrc + (size_t)(n0 + srow) * K + schk * 8;
        bg1 = bg0 + (size_t)64 * K;
    }

    uint4 stA_a0, stA_a1, stA_b0, stA_b1;        // two register stage-sets
    uint4 stB_a0, stB_a1, stB_b0, stB_b1;

#define LD_STAGE(P, CH) {                                                   \
        P##_a0 = *(const uint4*)(wg0 + (size_t)(CH) * 32);                  \
        P##_a1 = *(const uint4*)(wg1 + (size_t)(CH) * 32);                  \
        P##_b0 = *(const uint4*)(bg0 + (size_t)(CH) * 32);                  \
        P##_b1 = *(const uint4*)(bg1 + (size_t)(CH) * 32); }

#define ST_STAGE(P, BUF) {                                                  \
        *(uint4*)&sm.s.Wt[BUF][stw] = P##_a0;                               \
        *(uint4*)&sm.s.Wt[BUF][stw + 2048] = P##_a1;                        \
        *(uint4*)&sm.s.At[BUF][stw] = P##_b0;                               \
        *(uint4*)&sm.s.At[BUF][stw + 2048] = P##_b1; }

#define GEMM_BODY(BUF, P, CHW, CHL) {                                               \
        bf16x8 af[4], bf[4];                                                        \
        _Pragma("unroll")                                                           \
        for (int mt = 0; mt < 4; ++mt)                                              \
            af[mt] = *(const bf16x8*)&sm.s.Wt[BUF][wr * 2048 + (mt * 16 + ln) * 32 + rq]; \
        _Pragma("unroll")                                                           \
        for (int nt = 0; nt < 4; ++nt)                                              \
            bf[nt] = *(const bf16x8*)&sm.s.At[BUF][wc * 2048 + (nt * 16 + ln) * 32 + rq]; \
        _Pragma("unroll")                                                           \
        for (int mt = 0; mt < 4; ++mt)                                              \
            _Pragma("unroll")                                                       \
            for (int nt = 0; nt < 4; ++nt)                                          \
                acc[mt][nt] = __builtin_amdgcn_mfma_f32_16x16x32_bf16(af[mt], bf[nt], acc[mt][nt], 0, 0, 0); \
        if ((CHW) < NIT) {                                                          \
            ST_STAGE(P, (BUF) ^ 1)                                                  \
            if ((CHL) < NIT) LD_STAGE(P, (CHL))                                     \
            asm volatile("s_waitcnt lgkmcnt(0)" ::: "memory");                      \
            __builtin_amdgcn_s_barrier();                                           \
            __builtin_amdgcn_sched_barrier(0);                                      \
        } }

    // prologue: chunk0 -> LDS[0]; chunks 1,2 in flight across the barrier
    LD_STAGE(stA, 0)
    ST_STAGE(stA, 0)
    LD_STAGE(stA, 1)
    LD_STAGE(stB, 2)
    asm volatile("s_waitcnt lgkmcnt(0)" ::: "memory");
    __builtin_amdgcn_s_barrier();
    __builtin_amdgcn_sched_barrier(0);

    f32x4 acc[4][4] = {};
    for (int i2 = 0; i2 < NIT; i2 += 2) {
        GEMM_BODY(0, stA, i2 + 1, i2 + 3)
        GEMM_BODY(1, stB, i2 + 2, i2 + 4)
    }
#undef GEMM_BODY
#undef ST_STAGE
#undef LD_STAGE

    // ---- epilogue; D within a 16x16 frag: row = quad*4+reg, col = ln ----
    if (MODE == 2) {
        float* outp = (float*)outv;
        int h0 = n0 / 56;
        int hmin = max(0, (h0 >> 1) - 1);
#pragma unroll
        for (int hi = 0; hi < 2; ++hi) {        // two-pass over o-halves (pt = 64 rows)
            __syncthreads();
            for (int e = tid; e < 64 * 140; e += 256) {
                int o_l = e / 140, rem = e - o_l * 140;
                int s2 = rem / 28, w = rem - s2 * 28;
                int row = min(hmin + s2, 27);
                sm.pt[e] = ld_f(&Pb[((size_t)b * C2 + o0 + hi * 64 + o_l) * HW + row * 28 + w]);
            }
            __syncthreads();
            if (wr == hi) {
#pragma unroll
                for (int nt = 0; nt < 4; ++nt) {
                    int q = n0 + wc * 64 + nt * 16 + ln;
                    if (q < QW) {
                        int hq = q / 56, wq = q - hq * 56;
                        int hm = hq >> 1, wm = wq >> 1;
                        int hn = (hq & 1) ? min(hm + 1, 27) : max(hm - 1, 0);
                        int wn_ = (wq & 1) ? min(wm + 1, 27) : max(wm - 1, 0);
                        int rm_ = (hm - hmin) * 28, rn_ = (hn - hmin) * 28;
#pragma unroll
                        for (int mt = 0; mt < 4; ++mt)
#pragma unroll
                            for (int reg = 0; reg < 4; ++reg) {
                                int ol = mt * 16 + quad * 4 + reg;
                                int o = o0 + hi * 64 + ol;
                                const float* Pt = &sm.pt[ol * 140];
                                float up = 0.5625f * Pt[rm_ + wm] + 0.1875f * (Pt[rm_ + wn_] + Pt[rn_ + wm])
                                         + 0.0625f * Pt[rn_ + wn_];
                                float v = (acc[mt][nt][reg] + up) * sA[o] + sB[o];
                                outp[((size_t)b * C2 + o) * QW + q] = fmaxf(v, 0.f);
                            }
                    }
                }
            }
        }
    } else if (MODE == 0) {
        unsigned short* outp = (unsigned short*)outv;   // BcatT, pitch 1536, cols 0..511
#pragma unroll
        for (int nt = 0; nt < 4; ++nt) {
            int n = n0 + wc * 64 + nt * 16 + ln;
#pragma unroll
            for (int mt = 0; mt < 4; ++mt) {
                int ob = o0 + wr * 64 + mt * 16 + quad * 4;
                unsigned short pk[4];
#pragma unroll
                for (int reg = 0; reg < 4; ++reg) {
                    int o = ob + reg;
                    float v = acc[mt][nt][reg] * sA[o] + sB[o];
                    pk[reg] = f2bf(1.f / (1.f + expf(-v)));
                }
                *(uint2*)&outp[(size_t)n * 1536 + ob] = *(uint2*)pk;
            }
        }
    } else {
        unsigned short* outp = (unsigned short*)outv;   // Pb [b][o][784] bf16
#pragma unroll
        for (int nt = 0; nt < 4; ++nt) {
            int n = n0 + wc * 64 + nt * 16 + ln;
            int be = n / HW, pe = n - be * HW;
#pragma unroll
            for (int mt = 0; mt < 4; ++mt)
#pragma unroll
                for (int reg = 0; reg < 4; ++reg) {
                    int o = o0 + wr * 64 + mt * 16 + quad * 4 + reg;
                    outp[((size_t)be * C2 + o) * HW + pe] = f2bf(acc[mt][nt][reg]);
                }
        }
    }
}

extern "C" void kernel_launch(void* const* d_in, const int* in_sizes, int n_in,
                              void* d_out, int out_size, void* d_ws, size_t ws_size,
                              hipStream_t stream) {
    const float* y       = (const float*)d_in[0];
    const float* x       = (const float*)d_in[1];
    const float* fc1_w   = (const float*)d_in[2];
    const float* fc2_w   = (const float*)d_in[3];
    const float* conv_w  = (const float*)d_in[4];
    const float* conv_b  = (const float*)d_in[5];
    const float* conv1_w = (const float*)d_in[6];
    const float* conv1_b = (const float*)d_in[7];
    const float* bn_g    = (const float*)d_in[8];
    const float* bn_b    = (const float*)d_in[9];
    const float* bn_m    = (const float*)d_in[10];
    const float* bn_v    = (const float*)d_in[11];
    const float* dw_w    = (const float*)d_in[12];
    const float* dw_b    = (const float*)d_in[13];
    float* out = (float*)d_out;

    // ---- d_out doubles as scratch for buffers that die before M2's epilogue ----
    // cov_bf(12.85M) + covT(12.85M) + BcatT(19.27M) = 44,957,696 B <= out 51,380,224 B.
    // M2 writes every out element (o: 4x128 tiles, q: guarded to 3136) -> full overwrite.
    unsigned short* cov_bf = (unsigned short*)d_out;         // 8*1024*784
    unsigned short* covT   = cov_bf + (size_t)B * C * HW;    // 8*784*1024
    unsigned short* BcatT  = covT + (size_t)B * HW * C;      // 6272*1536

    // ---- ws carve: 35,297,280 B (< Round-2-proven 45,389,824 extent) ----
    float* ws  = (float*)d_ws;
    float* s0  = ws;                 // 4096
    float* att = ws + 4096;          // 4096
    float* sA  = ws + 8192;          // 512
    float* sB0 = ws + 8704;          // 512
    float* sB1 = ws + 9216;          // 512 -> header ends at float 9728 (byte 38912, 16B-aligned)
    unsigned short* w0b  = (unsigned short*)(ws + 9728);     // 512*1024 sh
    unsigned short* w1p0 = w0b + (size_t)C2 * C;             // 512*512 sh
    unsigned short* w1pT = w1p0 + (size_t)C2 * C2;           // 512*1536 sh
    unsigned short* yT   = w1pT + (size_t)C2 * 1536;         // 8*3136*512 sh
    unsigned short* Pb   = yT + (size_t)B * QW * C2;         // 8*512*784 sh

    gap_kernel<<<B * C2, 256, 0, stream>>>(y, s0);
    se_fc_kernel<<<B, 256, 0, stream>>>(s0, fc1_w, fc2_w, att);
    pack_w<<<C2, 256, 0, stream>>>(conv_w, conv_b, conv1_w, conv1_b,
                                   bn_g, bn_b, bn_m, bn_v,
                                   w0b, w1p0, w1pT, sA, sB0, sB1);
    dwcov_kernel<<<B * C, 256, 0, stream>>>(x, dw_w, dw_b, cov_bf);
    // xT: x[b][c][p] -> BcatT[(b,p)][512+c]
    transpose_pass<float, false><<<dim3(13, 16, B), 256, 0, stream>>>(
        x, BcatT, nullptr, C, HW, 1536, 512);
    // covT: cov[b][c][p] -> covT[(b,p)][c]
    transpose_pass<unsigned short, false><<<dim3(13, 16, B), 256, 0, stream>>>(
        cov_bf, covT, nullptr, C, HW, C, 0);
    // yT: y[b][c][q]*att[b][c] -> yT[(b,q)][c]  (att folded -> A of M2 is batch-independent)
    transpose_pass<float, true><<<dim3(49, 8, B), 256, 0, stream>>>(
        y, yT, att, C2, QW, C2, 0);
    // M0: x2s = sigmoid(bn(conv(cov))) -> BcatT cols 0..511  (49 tiles: 7,6x7 -> grid 8*4*7)
    mfma_gemm<0, 1024><<<dim3(224), 256, 0, stream>>>(w0b, covT, nullptr, sA, sB0, BcatT);
    // M1: Pb = w1[:,512:]·[x2s|x]  (bf16)
    mfma_gemm<1, 1536><<<dim3(224), 256, 0, stream>>>(w1pT, BcatT, nullptr, sA, sB0, Pb);
    // M2: out = relu(bn(w1p0·yT + up(Pb)))  (25 tiles: 4,3x7 -> grid 8*4*4 per batch)
    mfma_gemm<2, 512><<<dim3(128, 1, B), 256, 0, stream>>>(w1p0, yT, Pb, sA, sB1, out);
}

// Round 6
// 313.303 us; speedup vs baseline: 1.1234x; 1.1234x over previous
//
#include <hip/hip_runtime.h>
#include <math.h>

#define EPSV 1e-5f
#define B 8
#define C 1024
#define C2 512
#define RK 73
#define HW 784      // 28*28
#define QW 3136     // 56*56

typedef __attribute__((ext_vector_type(8))) short bf16x8;
typedef __attribute__((ext_vector_type(4))) float f32x4;

__device__ __forceinline__ unsigned short f2bf(float f) {
    unsigned u = __float_as_uint(f);
    return (unsigned short)((u + 0x7fffu + ((u >> 16) & 1u)) >> 16);
}
__device__ __forceinline__ float ld_f(const float* p) { return *p; }
__device__ __forceinline__ float ld_f(const unsigned short* p) {
    return __uint_as_float(((unsigned)*p) << 16);
}

// ---------- zero s0 before yT's atomic accumulation ----------
__global__ void zero_s0(float* __restrict__ s0) {
    s0[blockIdx.x * 256 + threadIdx.x] = 0.f;
}

// ---------- SE FC layers (s0 holds raw sums; scale by 1/QW here) ----------
__global__ void se_fc_kernel(const float* __restrict__ s0,
                             const float* __restrict__ fc1_w,
                             const float* __restrict__ fc2_w,
                             float* __restrict__ att) {
    int b = blockIdx.x;
    __shared__ float sv[C2];
    __shared__ float hv[RK];
    for (int i = threadIdx.x; i < C2; i += 256) sv[i] = s0[b * C2 + i] * (1.0f / QW);
    __syncthreads();
    if (threadIdx.x < RK) {
        float acc = 0.f;
        const float4* wr4 = (const float4*)(fc1_w + threadIdx.x * C2);
        const float4* sv4 = (const float4*)sv;
#pragma unroll 16
        for (int k = 0; k < C2 / 4; ++k) {
            float4 w4 = wr4[k], s4 = sv4[k];
            acc += w4.x * s4.x + w4.y * s4.y + w4.z * s4.z + w4.w * s4.w;
        }
        hv[threadIdx.x] = fmaxf(acc, 0.f);
    }
    __syncthreads();
    for (int o = threadIdx.x; o < C2; o += 256) {
        float acc = 0.f;
        const float* wr = fc2_w + o * RK;
#pragma unroll
        for (int j = 0; j < RK; ++j) acc += wr[j] * hv[j];
        att[b * C2 + o] = 1.f / (1.f + expf(-acc));
    }
}

// ---------- depthwise 3x3 conv + row-centered cov -> bf16 ----------
__global__ void dwcov_kernel(const float* __restrict__ x,
                             const float* __restrict__ dw_w,
                             const float* __restrict__ dw_b,
                             unsigned short* __restrict__ cov) {
    int bc = blockIdx.x;
    int c = bc & (C - 1);
    __shared__ float xs[HW];
    __shared__ float x1[HW];
    __shared__ float rm[28];
    const float* px = x + (size_t)bc * HW;
    for (int i = threadIdx.x; i < HW; i += 256) xs[i] = px[i];
    float wk[9];
#pragma unroll
    for (int j = 0; j < 9; ++j) wk[j] = dw_w[c * 9 + j];
    float bias = dw_b[c];
    __syncthreads();
    for (int p = threadIdx.x; p < HW; p += 256) {
        int h = p / 28, w = p - h * 28;
        float acc = bias;
#pragma unroll
        for (int dh = 0; dh < 3; ++dh) {
            int hh = h + dh - 1;
            if (hh < 0 || hh >= 28) continue;
#pragma unroll
            for (int dw = 0; dw < 3; ++dw) {
                int ww = w + dw - 1;
                if (ww < 0 || ww >= 28) continue;
                acc += xs[hh * 28 + ww] * wk[dh * 3 + dw];
            }
        }
        x1[p] = acc;
    }
    __syncthreads();
    if (threadIdx.x < 28) {
        float s = 0.f;
        for (int w = 0; w < 28; ++w) s += x1[threadIdx.x * 28 + w];
        rm[threadIdx.x] = s * (1.f / 28.f);
    }
    __syncthreads();
    unsigned short* pc = cov + (size_t)bc * HW;
    for (int p = threadIdx.x; p < HW; p += 256) {
        int h = p / 28, g = p - h * 28;
        float mh = rm[h], mg = rm[g];
        float acc = 0.f;
        for (int w = 0; w < 28; ++w)
            acc += (x1[h * 28 + w] - mh) * (x1[g * 28 + w] - mg);
        pc[p] = f2bf(acc * (1.f / 27.f));
    }
}

// ---------- pack weights bf16; fold att into per-batch w1y; fold bias+bn ----------
__global__ void pack_w(const float* __restrict__ conv_w, const float* __restrict__ conv_b,
                       const float* __restrict__ conv1_w, const float* __restrict__ conv1_b,
                       const float* __restrict__ bn_g, const float* __restrict__ bn_b,
                       const float* __restrict__ bn_m, const float* __restrict__ bn_v,
                       const float* __restrict__ att,
                       unsigned short* __restrict__ w0b, unsigned short* __restrict__ w1y,
                       unsigned short* __restrict__ w1pT,
                       float* __restrict__ sA, float* __restrict__ sB0, float* __restrict__ sB1) {
    int o = blockIdx.x, t = threadIdx.x;
    for (int i = t; i < C; i += 256) w0b[(size_t)o * C + i] = f2bf(conv_w[(size_t)o * C + i]);
    for (int i = t; i < 1536; i += 256) w1pT[(size_t)o * 1536 + i] = f2bf(conv1_w[(size_t)o * 2048 + 512 + i]);
#pragma unroll
    for (int b = 0; b < B; ++b)
        for (int c2 = t; c2 < C2; c2 += 256)
            w1y[((size_t)b * C2 + o) * C2 + c2] = f2bf(conv1_w[(size_t)o * 2048 + c2] * att[b * C2 + c2]);
    if (t == 0) {
        float sc = rsqrtf(bn_v[o] + EPSV) * bn_g[o];
        float bi = bn_b[o] - bn_m[o] * sc;
        sA[o] = sc;
        sB0[o] = conv_b[o] * sc + bi;
        sB1[o] = conv1_b[o] * sc + bi;
    }
}

// ---------- tiled transpose+convert: src[b][rows][cols] -> dst[(b,col)][dpitch]+doff ----------
// GAP: additionally reduce each channel-row's 64 staged values and atomicAdd into
// s0[b*rows + c] (fuses the old gap_kernel's 51.4MB y re-read into this pass).
template<typename ST, bool GAP>
__global__ __launch_bounds__(256)
void transpose_pass(const ST* __restrict__ src, unsigned short* __restrict__ dst,
                    float* __restrict__ s0,
                    int rows, int cols, int dpitch, int doff) {
    int b = blockIdx.z;
    int c0 = blockIdx.y * 64, p0 = blockIdx.x * 64;
    __shared__ float ts[64][65];
    int tid = threadIdx.x;
    int pl = tid & 63, r0 = tid >> 6;
    const ST* sb = src + ((size_t)b * rows + c0) * cols + p0;
    if (p0 + pl < cols) {
#pragma unroll
        for (int j = 0; j < 16; ++j) {
            int cl = r0 + j * 4;
            ts[cl][pl] = ld_f(&sb[(size_t)cl * cols + pl]);
        }
    }
    __syncthreads();
    int cl = tid & 63;
#pragma unroll
    for (int j = 0; j < 16; ++j) {
        int pl2 = r0 + j * 4;
        if (p0 + pl2 < cols)
            dst[((size_t)b * cols + p0 + pl2) * dpitch + doff + c0 + cl] = f2bf(ts[cl][pl2]);
    }
    if (GAP) {
        if (tid < 64) {
            float s = 0.f;
#pragma unroll
            for (int i = 0; i < 64; ++i) s += ts[tid][i];   // banks (tid*65+i)%32 distinct per tid
            atomicAdd(&s0[b * rows + c0 + tid], s);
        }
    }
}

// ---------- MFMA GEMM: 64o x 64n, BK=32, 2-deep reg prefetch, raw-barrier pipeline ----------
// (R4 structure -- proven best. 128-wide tiles starve the grid and regress; the LDS
// conflict counter lives in the MODE2 epilogue pt reads and is ~2.6us total -- benign.)
// Pipeline: two register stage-sets hold chunks i+1/i+2; loads stay in flight across
// raw s_barrier (lgkmcnt-only publish, no vmcnt(0) drain per K-step).
// XCD classes balanced & bijective: NT=49 -> 7,6*7; NT=98 -> 13,13,12*6. XCD = bx%8.
// MODE 0: A=w0b    K=1024, B=covT  [(b,p)][1024]; epi bn+sigmoid -> BcatT cols 0..511
// MODE 1: A=w1pT   K=1536, B=BcatT [(b,p)][1536]; epi f2bf -> Pb [b][o][784]
// MODE 2: A=w1y[b] K=512,  B=yT    [(b,q)][512];  epi (acc+up(Pb))*bn relu -> out
template<int MODE, int K>
__global__ __launch_bounds__(256)
void mfma_gemm(const unsigned short* __restrict__ wpk,
               const unsigned short* __restrict__ bsrc,
               const unsigned short* __restrict__ Pb,
               const float* __restrict__ sA, const float* __restrict__ sB,
               void* __restrict__ outv) {
    constexpr int NIT = K / 32;                  // 32 / 48 / 16 -- all even
    constexpr int NT  = (MODE == 2) ? 49 : 98;   // n-tiles
    constexpr int QN = NT >> 3, REM = NT & 7;
    int bx = blockIdx.x;
    int r = bx & 7, ii = bx >> 3;
    int og = ii & 7, s = ii >> 3;
    int cnt = QN + (r < REM ? 1 : 0);
    if (s >= cnt) return;
    int t = (r < REM ? r * (QN + 1) : REM * (QN + 1) + (r - REM) * QN) + s;
    int o0 = og * 64;
    int n0 = t * 64;
    int b = blockIdx.z;
    union SM {
        struct { __align__(16) unsigned short Wt[2][2560]; __align__(16) unsigned short At[2][2560]; } s;
        float pt[(MODE == 2) ? 64 * 84 : 4];
    };
    __shared__ SM sm;
    int tid = threadIdx.x;
    int lane = tid & 63, wv = tid >> 6;
    int ln = lane & 15, quad = lane >> 4;
    int o_w = (wv >> 1) * 32, q_w = (wv & 1) * 32;
    int swr = tid >> 2, swk = (tid & 3) * 8;   // 16B staging: row, k-off
    const unsigned short* wp = (MODE == 2) ? wpk + (size_t)b * C2 * C2 : wpk;
    const unsigned short* wg = wp + (size_t)(o0 + swr) * K + swk;
    const unsigned short* bg = bsrc + ((size_t)((MODE == 2) ? b * QW : 0) + n0 + swr) * K + swk;

    uint4 stA_a, stA_b, stB_a, stB_b;          // two register stage-sets (A,B each)

#define LD_STAGE(P, CH) {                                                   \
        P##_a = *(const uint4*)(wg + (size_t)(CH) * 32);                    \
        P##_b = *(const uint4*)(bg + (size_t)(CH) * 32); }

#define ST_STAGE(P, BUF) {                                                  \
        *(uint4*)&sm.s.Wt[BUF][swr * 40 + swk] = P##_a;                     \
        *(uint4*)&sm.s.At[BUF][swr * 40 + swk] = P##_b; }

#define GEMM_BODY(BUF, P, CHW, CHL) {                                               \
        bf16x8 af0 = *(const bf16x8*)&sm.s.Wt[BUF][(o_w + ln) * 40 + quad * 8];     \
        bf16x8 af1 = *(const bf16x8*)&sm.s.Wt[BUF][(o_w + 16 + ln) * 40 + quad * 8];\
        bf16x8 bf0 = *(const bf16x8*)&sm.s.At[BUF][(q_w + ln) * 40 + quad * 8];     \
        bf16x8 bf1 = *(const bf16x8*)&sm.s.At[BUF][(q_w + 16 + ln) * 40 + quad * 8];\
        acc[0][0] = __builtin_amdgcn_mfma_f32_16x16x32_bf16(af0, bf0, acc[0][0], 0, 0, 0); \
        acc[0][1] = __builtin_amdgcn_mfma_f32_16x16x32_bf16(af0, bf1, acc[0][1], 0, 0, 0); \
        acc[1][0] = __builtin_amdgcn_mfma_f32_16x16x32_bf16(af1, bf0, acc[1][0], 0, 0, 0); \
        acc[1][1] = __builtin_amdgcn_mfma_f32_16x16x32_bf16(af1, bf1, acc[1][1], 0, 0, 0); \
        if ((CHW) < NIT) {                                                          \
            ST_STAGE(P, (BUF) ^ 1)                                                  \
            if ((CHL) < NIT) LD_STAGE(P, (CHL))                                     \
            asm volatile("s_waitcnt lgkmcnt(0)" ::: "memory");                      \
            __builtin_amdgcn_s_barrier();                                           \
            __builtin_amdgcn_sched_barrier(0);                                      \
        } }

    // prologue: chunk0 -> LDS[0]; chunks 1,2 in flight across the barrier
    LD_STAGE(stA, 0)
    ST_STAGE(stA, 0)
    LD_STAGE(stA, 1)
    LD_STAGE(stB, 2)
    asm volatile("s_waitcnt lgkmcnt(0)" ::: "memory");
    __builtin_amdgcn_s_barrier();
    __builtin_amdgcn_sched_barrier(0);

    f32x4 acc[2][2] = {};
    for (int i2 = 0; i2 < NIT; i2 += 2) {
        GEMM_BODY(0, stA, i2 + 1, i2 + 3)
        GEMM_BODY(1, stB, i2 + 2, i2 + 4)
    }
#undef GEMM_BODY
#undef ST_STAGE
#undef LD_STAGE

    // ---- epilogue; D: row = quad*4+reg, col = ln ----
    if (MODE == 2) {
        float* outp = (float*)outv;
        int h0 = n0 / 56;
        int hmin = (h0 & 1) ? (h0 >> 1) : max(0, (h0 >> 1) - 1);
        // batched Pb staging: 21 independent loads in flight (was a rolled serial
        // load->wait->ds_write loop = ~21 x latency per block), then publish to LDS.
        float stv[21];
#pragma unroll
        for (int j = 0; j < 21; ++j) {
            int e = tid + j * 256;               // 21*256 == 64*84 exactly
            int o_l = e / 84, rem = e - o_l * 84;
            int s2 = rem / 28, w = rem - s2 * 28;
            int row = min(hmin + s2, 27);
            stv[j] = ld_f(&Pb[((size_t)b * C2 + o0 + o_l) * HW + row * 28 + w]);
        }
        __syncthreads();                          // all waves done with K-loop LDS
#pragma unroll
        for (int j = 0; j < 21; ++j) sm.pt[tid + j * 256] = stv[j];
        __syncthreads();
#pragma unroll
        for (int nt = 0; nt < 2; ++nt) {
            int q = n0 + q_w + nt * 16 + ln;
            int hq = q / 56, wq = q - hq * 56;
            int hm = hq >> 1, wm = wq >> 1;
            int hn = (hq & 1) ? min(hm + 1, 27) : max(hm - 1, 0);
            int wn_ = (wq & 1) ? min(wm + 1, 27) : max(wm - 1, 0);
            int rm_ = (hm - hmin) * 28, rn_ = (hn - hmin) * 28;
#pragma unroll
            for (int mt = 0; mt < 2; ++mt)
#pragma unroll
                for (int reg = 0; reg < 4; ++reg) {
                    int ol = o_w + mt * 16 + quad * 4 + reg;
                    int o = o0 + ol;
                    const float* Pt = &sm.pt[ol * 84];
                    float up = 0.5625f * Pt[rm_ + wm] + 0.1875f * (Pt[rm_ + wn_] + Pt[rn_ + wm])
                             + 0.0625f * Pt[rn_ + wn_];
                    float v = (acc[mt][nt][reg] + up) * sA[o] + sB[o];
                    outp[((size_t)b * C2 + o) * QW + q] = fmaxf(v, 0.f);
                }
        }
    } else if (MODE == 0) {
        unsigned short* outp = (unsigned short*)outv;   // BcatT, pitch 1536, cols 0..511
#pragma unroll
        for (int nt = 0; nt < 2; ++nt) {
            int n = n0 + q_w + nt * 16 + ln;
#pragma unroll
            for (int mt = 0; mt < 2; ++mt) {
                int ob = o0 + o_w + mt * 16 + quad * 4;
                unsigned short pk[4];
#pragma unroll
                for (int reg = 0; reg < 4; ++reg) {
                    int o = ob + reg;
                    float v = acc[mt][nt][reg] * sA[o] + sB[o];
                    pk[reg] = f2bf(1.f / (1.f + expf(-v)));
                }
                *(uint2*)&outp[(size_t)n * 1536 + ob] = *(uint2*)pk;
            }
        }
    } else {
        unsigned short* outp = (unsigned short*)outv;   // Pb [b][o][784] bf16
#pragma unroll
        for (int nt = 0; nt < 2; ++nt) {
            int n = n0 + q_w + nt * 16 + ln;
            int be = n / HW, pe = n - be * HW;
#pragma unroll
            for (int mt = 0; mt < 2; ++mt)
#pragma unroll
                for (int reg = 0; reg < 4; ++reg) {
                    int o = o0 + o_w + mt * 16 + quad * 4 + reg;
                    outp[((size_t)be * C2 + o) * HW + pe] = f2bf(acc[mt][nt][reg]);
                }
        }
    }
}

extern "C" void kernel_launch(void* const* d_in, const int* in_sizes, int n_in,
                              void* d_out, int out_size, void* d_ws, size_t ws_size,
                              hipStream_t stream) {
    const float* y       = (const float*)d_in[0];
    const float* x       = (const float*)d_in[1];
    const float* fc1_w   = (const float*)d_in[2];
    const float* fc2_w   = (const float*)d_in[3];
    const float* conv_w  = (const float*)d_in[4];
    const float* conv_b  = (const float*)d_in[5];
    const float* conv1_w = (const float*)d_in[6];
    const float* conv1_b = (const float*)d_in[7];
    const float* bn_g    = (const float*)d_in[8];
    const float* bn_b    = (const float*)d_in[9];
    const float* bn_m    = (const float*)d_in[10];
    const float* bn_v    = (const float*)d_in[11];
    const float* dw_w    = (const float*)d_in[12];
    const float* dw_b    = (const float*)d_in[13];
    float* out = (float*)d_out;

    // ---- d_out doubles as scratch for buffers that die before M2's epilogue ----
    // cov_bf(12.85M) + covT(12.85M) + BcatT(19.27M) = 44,957,696 B <= out 51,380,224 B.
    // M2 writes every out element (o: 8x64 tiles, q: 49x64 tiles exact) -> full overwrite.
    unsigned short* cov_bf = (unsigned short*)d_out;         // 8*1024*784
    unsigned short* covT   = cov_bf + (size_t)B * C * HW;    // 8*784*1024
    unsigned short* BcatT  = covT + (size_t)B * HW * C;      // 6272*1536

    // ---- ws carve: 39,491,584 B (< Round-2-proven 45,389,824 extent) ----
    float* ws  = (float*)d_ws;
    float* s0  = ws;                 // 4096
    float* att = ws + 4096;          // 4096
    float* sA  = ws + 8192;          // 512
    float* sB0 = ws + 8704;          // 512
    float* sB1 = ws + 9216;          // 512 -> header ends at float 9728 (byte 38912, 16B-aligned)
    unsigned short* w0b  = (unsigned short*)(ws + 9728);     // 512*1024 sh
    unsigned short* w1y  = w0b + (size_t)C2 * C;             // 8*512*512 sh
    unsigned short* w1pT = w1y + (size_t)B * C2 * C2;        // 512*1536 sh
    unsigned short* yT   = w1pT + (size_t)C2 * 1536;         // 8*3136*512 sh
    unsigned short* Pb   = yT + (size_t)B * QW * C2;         // 8*512*784 sh

    // gap fused into yT: zero s0, transpose y (read ONCE) with atomic channel sums
    zero_s0<<<16, 256, 0, stream>>>(s0);
    transpose_pass<float, true><<<dim3(49, 8, B), 256, 0, stream>>>(
        y, yT, s0, C2, QW, C2, 0);
    se_fc_kernel<<<B, 256, 0, stream>>>(s0, fc1_w, fc2_w, att);
    pack_w<<<C2, 256, 0, stream>>>(conv_w, conv_b, conv1_w, conv1_b,
                                   bn_g, bn_b, bn_m, bn_v, att,
                                   w0b, w1y, w1pT, sA, sB0, sB1);
    dwcov_kernel<<<B * C, 256, 0, stream>>>(x, dw_w, dw_b, cov_bf);
    // xT: x[b][c][p] -> BcatT[(b,p)][512+c]
    transpose_pass<float, false><<<dim3(13, 16, B), 256, 0, stream>>>(
        x, BcatT, nullptr, C, HW, 1536, 512);
    // covT: cov[b][c][p] -> covT[(b,p)][c]
    transpose_pass<unsigned short, false><<<dim3(13, 16, B), 256, 0, stream>>>(
        cov_bf, covT, nullptr, C, HW, C, 0);
    // M0: x2s = sigmoid(bn(conv(cov))) -> BcatT cols 0..511  (98 tiles: 13,13,12x6 -> grid 8*8*13)
    mfma_gemm<0, 1024><<<dim3(832), 256, 0, stream>>>(w0b, covT, nullptr, sA, sB0, BcatT);
    // M1: Pb = w1[:,512:]·[x2s|x]  (bf16)
    mfma_gemm<1, 1536><<<dim3(832), 256, 0, stream>>>(w1pT, BcatT, nullptr, sA, sB0, Pb);
    // M2: out = relu(bn(w1y[b]·yT + up(Pb)))  (49 tiles: 7,6x7 -> grid 8*8*7 per batch)
    mfma_gemm<2, 512><<<dim3(448, 1, B), 256, 0, stream>>>(w1y, yT, Pb, sA, sB1, out);
}

// Round 7
// 307.376 us; speedup vs baseline: 1.1451x; 1.0193x over previous
//
#include <hip/hip_runtime.h>
#include <math.h>

#define EPSV 1e-5f
#define B 8
#define C 1024
#define C2 512
#define RK 73
#define HW 784      // 28*28
#define QW 3136     // 56*56

typedef __attribute__((ext_vector_type(8))) short bf16x8;
typedef __attribute__((ext_vector_type(4))) float f32x4;

__device__ __forceinline__ unsigned short f2bf(float f) {
    unsigned u = __float_as_uint(f);
    return (unsigned short)((u + 0x7fffu + ((u >> 16) & 1u)) >> 16);
}
__device__ __forceinline__ float ld_f(const float* p) { return *p; }
__device__ __forceinline__ float ld_f(const unsigned short* p) {
    return __uint_as_float(((unsigned)*p) << 16);
}

// ---------- zero s0 before yT's atomic accumulation ----------
__global__ void zero_s0(float* __restrict__ s0) {
    s0[blockIdx.x * 256 + threadIdx.x] = 0.f;
}

// ---------- SE FC layers (s0 holds raw sums; scale by 1/QW here) ----------
__global__ void se_fc_kernel(const float* __restrict__ s0,
                             const float* __restrict__ fc1_w,
                             const float* __restrict__ fc2_w,
                             float* __restrict__ att) {
    int b = blockIdx.x;
    __shared__ float sv[C2];
    __shared__ float hv[RK];
    for (int i = threadIdx.x; i < C2; i += 256) sv[i] = s0[b * C2 + i] * (1.0f / QW);
    __syncthreads();
    if (threadIdx.x < RK) {
        float acc = 0.f;
        const float4* wr4 = (const float4*)(fc1_w + threadIdx.x * C2);
        const float4* sv4 = (const float4*)sv;
#pragma unroll 16
        for (int k = 0; k < C2 / 4; ++k) {
            float4 w4 = wr4[k], s4 = sv4[k];
            acc += w4.x * s4.x + w4.y * s4.y + w4.z * s4.z + w4.w * s4.w;
        }
        hv[threadIdx.x] = fmaxf(acc, 0.f);
    }
    __syncthreads();
    for (int o = threadIdx.x; o < C2; o += 256) {
        float acc = 0.f;
        const float* wr = fc2_w + o * RK;
#pragma unroll
        for (int j = 0; j < RK; ++j) acc += wr[j] * hv[j];
        att[b * C2 + o] = 1.f / (1.f + expf(-acc));
    }
}

// ---------- depthwise 3x3 conv + row-centered cov -> bf16 ----------
__global__ void dwcov_kernel(const float* __restrict__ x,
                             const float* __restrict__ dw_w,
                             const float* __restrict__ dw_b,
                             unsigned short* __restrict__ cov) {
    int bc = blockIdx.x;
    int c = bc & (C - 1);
    __shared__ float xs[HW];
    __shared__ float x1[HW];
    __shared__ float rm[28];
    const float* px = x + (size_t)bc * HW;
    for (int i = threadIdx.x; i < HW; i += 256) xs[i] = px[i];
    float wk[9];
#pragma unroll
    for (int j = 0; j < 9; ++j) wk[j] = dw_w[c * 9 + j];
    float bias = dw_b[c];
    __syncthreads();
    for (int p = threadIdx.x; p < HW; p += 256) {
        int h = p / 28, w = p - h * 28;
        float acc = bias;
#pragma unroll
        for (int dh = 0; dh < 3; ++dh) {
            int hh = h + dh - 1;
            if (hh < 0 || hh >= 28) continue;
#pragma unroll
            for (int dw = 0; dw < 3; ++dw) {
                int ww = w + dw - 1;
                if (ww < 0 || ww >= 28) continue;
                acc += xs[hh * 28 + ww] * wk[dh * 3 + dw];
            }
        }
        x1[p] = acc;
    }
    __syncthreads();
    if (threadIdx.x < 28) {
        float s = 0.f;
        for (int w = 0; w < 28; ++w) s += x1[threadIdx.x * 28 + w];
        rm[threadIdx.x] = s * (1.f / 28.f);
    }
    __syncthreads();
    unsigned short* pc = cov + (size_t)bc * HW;
    for (int p = threadIdx.x; p < HW; p += 256) {
        int h = p / 28, g = p - h * 28;
        float mh = rm[h], mg = rm[g];
        float acc = 0.f;
        for (int w = 0; w < 28; ++w)
            acc += (x1[h * 28 + w] - mh) * (x1[g * 28 + w] - mg);
        pc[p] = f2bf(acc * (1.f / 27.f));
    }
}

// ---------- pack weights bf16; fold att into per-batch w1y; fold bias+bn ----------
__global__ void pack_w(const float* __restrict__ conv_w, const float* __restrict__ conv_b,
                       const float* __restrict__ conv1_w, const float* __restrict__ conv1_b,
                       const float* __restrict__ bn_g, const float* __restrict__ bn_b,
                       const float* __restrict__ bn_m, const float* __restrict__ bn_v,
                       const float* __restrict__ att,
                       unsigned short* __restrict__ w0b, unsigned short* __restrict__ w1y,
                       unsigned short* __restrict__ w1pT,
                       float* __restrict__ sA, float* __restrict__ sB0, float* __restrict__ sB1) {
    int o = blockIdx.x, t = threadIdx.x;
    for (int i = t; i < C; i += 256) w0b[(size_t)o * C + i] = f2bf(conv_w[(size_t)o * C + i]);
    for (int i = t; i < 1536; i += 256) w1pT[(size_t)o * 1536 + i] = f2bf(conv1_w[(size_t)o * 2048 + 512 + i]);
#pragma unroll
    for (int b = 0; b < B; ++b)
        for (int c2 = t; c2 < C2; c2 += 256)
            w1y[((size_t)b * C2 + o) * C2 + c2] = f2bf(conv1_w[(size_t)o * 2048 + c2] * att[b * C2 + c2]);
    if (t == 0) {
        float sc = rsqrtf(bn_v[o] + EPSV) * bn_g[o];
        float bi = bn_b[o] - bn_m[o] * sc;
        sA[o] = sc;
        sB0[o] = conv_b[o] * sc + bi;
        sB1[o] = conv1_b[o] * sc + bi;
    }
}

// ---------- tiled transpose+convert: src[b][rows][cols] -> dst[(b,col)][dpitch]+doff ----------
// Stores vectorized: each thread emits two short8 (16B) stores instead of 16 scalar
// ushort stores (128B/wave-instr -> 1KB/wave-instr).
// GAP: additionally reduce each channel-row's 64 staged values and atomicAdd into
// s0[b*rows + c] (fuses the old gap_kernel's 51.4MB y re-read into this pass).
template<typename ST, bool GAP>
__global__ __launch_bounds__(256)
void transpose_pass(const ST* __restrict__ src, unsigned short* __restrict__ dst,
                    float* __restrict__ s0,
                    int rows, int cols, int dpitch, int doff) {
    int b = blockIdx.z;
    int c0 = blockIdx.y * 64, p0 = blockIdx.x * 64;
    __shared__ float ts[64][65];
    int tid = threadIdx.x;
    int pl = tid & 63, r0 = tid >> 6;
    const ST* sb = src + ((size_t)b * rows + c0) * cols + p0;
    if (p0 + pl < cols) {
#pragma unroll
        for (int j = 0; j < 16; ++j) {
            int cl = r0 + j * 4;
            ts[cl][pl] = ld_f(&sb[(size_t)cl * cols + pl]);
        }
    }
    __syncthreads();
    int pl2b = tid >> 3, cl0 = (tid & 7) * 8;
#pragma unroll
    for (int j = 0; j < 2; ++j) {
        int pl2 = pl2b + j * 32;
        if (p0 + pl2 < cols) {
            unsigned short pk[8];
#pragma unroll
            for (int i = 0; i < 8; ++i) pk[i] = f2bf(ts[cl0 + i][pl2]);
            *(uint4*)&dst[((size_t)b * cols + p0 + pl2) * dpitch + doff + c0 + cl0] = *(uint4*)pk;
        }
    }
    if (GAP) {
        if (tid < 64) {
            float s = 0.f;
#pragma unroll
            for (int i = 0; i < 64; ++i) s += ts[tid][i];   // banks (tid*65+i)%32 distinct per tid
            atomicAdd(&s0[b * rows + c0 + tid], s);
        }
    }
}

// ---------- MFMA GEMM: 64o x 64n, BK=32, 2-deep reg prefetch, raw-barrier pipeline ----------
// LDS: unpadded 32-short (64B) rows with XOR swizzle -- 16B chunk c of row r lives at
// r*32 + 8*(c ^ ((r>>1)&3)), same XOR on read (read retrieves chunk q^((ln>>1)&3) ^
// ((row>>1)&3) = quad since (row>>1)&3 == (ln>>1)&3 for 16-aligned row bases).
// R5 measured this exact pattern: SQ_LDS_BANK_CONFLICT 6.5M -> 106K. The R4/R6 40-short
// padded rows were an 8-way conflict costing ~25k cy/CU (~20% of M2's window).
// Pipeline: two register stage-sets hold chunks i+1/i+2; loads stay in flight across
// raw s_barrier (lgkmcnt-only publish, no vmcnt(0) drain per K-step).
// XCD classes balanced & bijective: NT=49 -> 7,6*7; NT=98 -> 13,13,12*6. XCD = bx%8.
// MODE 0: A=w0b    K=1024, B=covT  [(b,p)][1024]; epi bn+sigmoid -> BcatT cols 0..511
// MODE 1: A=w1pT   K=1536, B=BcatT [(b,p)][1536]; epi f2bf -> Pb [b][o][784]
// MODE 2: A=w1y[b] K=512,  B=yT    [(b,q)][512];  epi (acc+up(Pb))*bn relu -> out
template<int MODE, int K>
__global__ __launch_bounds__(256)
void mfma_gemm(const unsigned short* __restrict__ wpk,
               const unsigned short* __restrict__ bsrc,
               const unsigned short* __restrict__ Pb,
               const float* __restrict__ sA, const float* __restrict__ sB,
               void* __restrict__ outv) {
    constexpr int NIT = K / 32;                  // 32 / 48 / 16 -- all even
    constexpr int NT  = (MODE == 2) ? 49 : 98;   // n-tiles
    constexpr int QN = NT >> 3, REM = NT & 7;
    int bx = blockIdx.x;
    int r = bx & 7, ii = bx >> 3;
    int og = ii & 7, s = ii >> 3;
    int cnt = QN + (r < REM ? 1 : 0);
    if (s >= cnt) return;
    int t = (r < REM ? r * (QN + 1) : REM * (QN + 1) + (r - REM) * QN) + s;
    int o0 = og * 64;
    int n0 = t * 64;
    int b = blockIdx.z;
    union SM {
        struct { __align__(16) unsigned short Wt[2][2048]; __align__(16) unsigned short At[2][2048]; } s;
        float pt[(MODE == 2) ? 64 * 84 : 4];
    };
    __shared__ SM sm;
    int tid = threadIdx.x;
    int lane = tid & 63, wv = tid >> 6;
    int ln = lane & 15, quad = lane >> 4;
    int o_w = (wv >> 1) * 32, q_w = (wv & 1) * 32;
    int swr = tid >> 2, swk = (tid & 3) * 8;   // 16B staging: row, k-off (global)
    int stw = swr * 32 + (((tid & 3) ^ ((swr >> 1) & 3)) << 3);   // swizzled LDS write off
    int rq  = (quad ^ ((ln >> 1) & 3)) << 3;                      // swizzled LDS read chunk
    const unsigned short* wp = (MODE == 2) ? wpk + (size_t)b * C2 * C2 : wpk;
    const unsigned short* wg = wp + (size_t)(o0 + swr) * K + swk;
    const unsigned short* bg = bsrc + ((size_t)((MODE == 2) ? b * QW : 0) + n0 + swr) * K + swk;

    uint4 stA_a, stA_b, stB_a, stB_b;          // two register stage-sets (A,B each)

#define LD_STAGE(P, CH) {                                                   \
        P##_a = *(const uint4*)(wg + (size_t)(CH) * 32);                    \
        P##_b = *(const uint4*)(bg + (size_t)(CH) * 32); }

#define ST_STAGE(P, BUF) {                                                  \
        *(uint4*)&sm.s.Wt[BUF][stw] = P##_a;                                \
        *(uint4*)&sm.s.At[BUF][stw] = P##_b; }

#define GEMM_BODY(BUF, P, CHW, CHL) {                                               \
        bf16x8 af0 = *(const bf16x8*)&sm.s.Wt[BUF][(o_w + ln) * 32 + rq];           \
        bf16x8 af1 = *(const bf16x8*)&sm.s.Wt[BUF][(o_w + 16 + ln) * 32 + rq];      \
        bf16x8 bf0 = *(const bf16x8*)&sm.s.At[BUF][(q_w + ln) * 32 + rq];           \
        bf16x8 bf1 = *(const bf16x8*)&sm.s.At[BUF][(q_w + 16 + ln) * 32 + rq];      \
        acc[0][0] = __builtin_amdgcn_mfma_f32_16x16x32_bf16(af0, bf0, acc[0][0], 0, 0, 0); \
        acc[0][1] = __builtin_amdgcn_mfma_f32_16x16x32_bf16(af0, bf1, acc[0][1], 0, 0, 0); \
        acc[1][0] = __builtin_amdgcn_mfma_f32_16x16x32_bf16(af1, bf0, acc[1][0], 0, 0, 0); \
        acc[1][1] = __builtin_amdgcn_mfma_f32_16x16x32_bf16(af1, bf1, acc[1][1], 0, 0, 0); \
        if ((CHW) < NIT) {                                                          \
            ST_STAGE(P, (BUF) ^ 1)                                                  \
            if ((CHL) < NIT) LD_STAGE(P, (CHL))                                     \
            asm volatile("s_waitcnt lgkmcnt(0)" ::: "memory");                      \
            __builtin_amdgcn_s_barrier();                                           \
            __builtin_amdgcn_sched_barrier(0);                                      \
        } }

    // prologue: chunk0 -> LDS[0]; chunks 1,2 in flight across the barrier
    LD_STAGE(stA, 0)
    ST_STAGE(stA, 0)
    LD_STAGE(stA, 1)
    LD_STAGE(stB, 2)
    asm volatile("s_waitcnt lgkmcnt(0)" ::: "memory");
    __builtin_amdgcn_s_barrier();
    __builtin_amdgcn_sched_barrier(0);

    f32x4 acc[2][2] = {};
    for (int i2 = 0; i2 < NIT; i2 += 2) {
        GEMM_BODY(0, stA, i2 + 1, i2 + 3)
        GEMM_BODY(1, stB, i2 + 2, i2 + 4)
    }
#undef GEMM_BODY
#undef ST_STAGE
#undef LD_STAGE

    // ---- epilogue; D: row = quad*4+reg, col = ln ----
    if (MODE == 2) {
        float* outp = (float*)outv;
        int h0 = n0 / 56;
        int hmin = (h0 & 1) ? (h0 >> 1) : max(0, (h0 >> 1) - 1);
        // batched Pb staging: 21 independent loads in flight, then publish to LDS.
        float stv[21];
#pragma unroll
        for (int j = 0; j < 21; ++j) {
            int e = tid + j * 256;               // 21*256 == 64*84 exactly
            int o_l = e / 84, rem = e - o_l * 84;
            int s2 = rem / 28, w = rem - s2 * 28;
            int row = min(hmin + s2, 27);
            stv[j] = ld_f(&Pb[((size_t)b * C2 + o0 + o_l) * HW + row * 28 + w]);
        }
        __syncthreads();                          // all waves done with K-loop LDS
#pragma unroll
        for (int j = 0; j < 21; ++j) sm.pt[tid + j * 256] = stv[j];
        __syncthreads();
#pragma unroll
        for (int nt = 0; nt < 2; ++nt) {
            int q = n0 + q_w + nt * 16 + ln;
            int hq = q / 56, wq = q - hq * 56;
            int hm = hq >> 1, wm = wq >> 1;
            int hn = (hq & 1) ? min(hm + 1, 27) : max(hm - 1, 0);
            int wn_ = (wq & 1) ? min(wm + 1, 27) : max(wm - 1, 0);
            int rm_ = (hm - hmin) * 28, rn_ = (hn - hmin) * 28;
#pragma unroll
            for (int mt = 0; mt < 2; ++mt)
#pragma unroll
                for (int reg = 0; reg < 4; ++reg) {
                    int ol = o_w + mt * 16 + quad * 4 + reg;
                    int o = o0 + ol;
                    const float* Pt = &sm.pt[ol * 84];
                    float up = 0.5625f * Pt[rm_ + wm] + 0.1875f * (Pt[rm_ + wn_] + Pt[rn_ + wm])
                             + 0.0625f * Pt[rn_ + wn_];
                    float v = (acc[mt][nt][reg] + up) * sA[o] + sB[o];
                    outp[((size_t)b * C2 + o) * QW + q] = fmaxf(v, 0.f);
                }
        }
    } else if (MODE == 0) {
        unsigned short* outp = (unsigned short*)outv;   // BcatT, pitch 1536, cols 0..511
#pragma unroll
        for (int nt = 0; nt < 2; ++nt) {
            int n = n0 + q_w + nt * 16 + ln;
#pragma unroll
            for (int mt = 0; mt < 2; ++mt) {
                int ob = o0 + o_w + mt * 16 + quad * 4;
                unsigned short pk[4];
#pragma unroll
                for (int reg = 0; reg < 4; ++reg) {
                    int o = ob + reg;
                    float v = acc[mt][nt][reg] * sA[o] + sB[o];
                    pk[reg] = f2bf(1.f / (1.f + expf(-v)));
                }
                *(uint2*)&outp[(size_t)n * 1536 + ob] = *(uint2*)pk;
            }
        }
    } else {
        unsigned short* outp = (unsigned short*)outv;   // Pb [b][o][784] bf16
#pragma unroll
        for (int nt = 0; nt < 2; ++nt) {
            int n = n0 + q_w + nt * 16 + ln;
            int be = n / HW, pe = n - be * HW;
#pragma unroll
            for (int mt = 0; mt < 2; ++mt)
#pragma unroll
                for (int reg = 0; reg < 4; ++reg) {
                    int o = o0 + o_w + mt * 16 + quad * 4 + reg;
                    outp[((size_t)be * C2 + o) * HW + pe] = f2bf(acc[mt][nt][reg]);
                }
        }
    }
}

extern "C" void kernel_launch(void* const* d_in, const int* in_sizes, int n_in,
                              void* d_out, int out_size, void* d_ws, size_t ws_size,
                              hipStream_t stream) {
    const float* y       = (const float*)d_in[0];
    const float* x       = (const float*)d_in[1];
    const float* fc1_w   = (const float*)d_in[2];
    const float* fc2_w   = (const float*)d_in[3];
    const float* conv_w  = (const float*)d_in[4];
    const float* conv_b  = (const float*)d_in[5];
    const float* conv1_w = (const float*)d_in[6];
    const float* conv1_b = (const float*)d_in[7];
    const float* bn_g    = (const float*)d_in[8];
    const float* bn_b    = (const float*)d_in[9];
    const float* bn_m    = (const float*)d_in[10];
    const float* bn_v    = (const float*)d_in[11];
    const float* dw_w    = (const float*)d_in[12];
    const float* dw_b    = (const float*)d_in[13];
    float* out = (float*)d_out;

    // ---- d_out doubles as scratch for buffers that die before M2's epilogue ----
    // cov_bf(12.85M) + covT(12.85M) + BcatT(19.27M) = 44,957,696 B <= out 51,380,224 B.
    // M2 writes every out element (o: 8x64 tiles, q: 49x64 tiles exact) -> full overwrite.
    unsigned short* cov_bf = (unsigned short*)d_out;         // 8*1024*784
    unsigned short* covT   = cov_bf + (size_t)B * C * HW;    // 8*784*1024
    unsigned short* BcatT  = covT + (size_t)B * HW * C;      // 6272*1536

    // ---- ws carve: 39,491,584 B (< Round-2-proven 45,389,824 extent) ----
    float* ws  = (float*)d_ws;
    float* s0  = ws;                 // 4096
    float* att = ws + 4096;          // 4096
    float* sA  = ws + 8192;          // 512
    float* sB0 = ws + 8704;          // 512
    float* sB1 = ws + 9216;          // 512 -> header ends at float 9728 (byte 38912, 16B-aligned)
    unsigned short* w0b  = (unsigned short*)(ws + 9728);     // 512*1024 sh
    unsigned short* w1y  = w0b + (size_t)C2 * C;             // 8*512*512 sh
    unsigned short* w1pT = w1y + (size_t)B * C2 * C2;        // 512*1536 sh
    unsigned short* yT   = w1pT + (size_t)C2 * 1536;         // 8*3136*512 sh
    unsigned short* Pb   = yT + (size_t)B * QW * C2;         // 8*512*784 sh

    // gap fused into yT: zero s0, transpose y (read ONCE) with atomic channel sums
    zero_s0<<<16, 256, 0, stream>>>(s0);
    transpose_pass<float, true><<<dim3(49, 8, B), 256, 0, stream>>>(
        y, yT, s0, C2, QW, C2, 0);
    se_fc_kernel<<<B, 256, 0, stream>>>(s0, fc1_w, fc2_w, att);
    pack_w<<<C2, 256, 0, stream>>>(conv_w, conv_b, conv1_w, conv1_b,
                                   bn_g, bn_b, bn_m, bn_v, att,
                                   w0b, w1y, w1pT, sA, sB0, sB1);
    dwcov_kernel<<<B * C, 256, 0, stream>>>(x, dw_w, dw_b, cov_bf);
    // xT: x[b][c][p] -> BcatT[(b,p)][512+c]
    transpose_pass<float, false><<<dim3(13, 16, B), 256, 0, stream>>>(
        x, BcatT, nullptr, C, HW, 1536, 512);
    // covT: cov[b][c][p] -> covT[(b,p)][c]
    transpose_pass<unsigned short, false><<<dim3(13, 16, B), 256, 0, stream>>>(
        cov_bf, covT, nullptr, C, HW, C, 0);
    // M0: x2s = sigmoid(bn(conv(cov))) -> BcatT cols 0..511  (98 tiles: 13,13,12x6 -> grid 8*8*13)
    mfma_gemm<0, 1024><<<dim3(832), 256, 0, stream>>>(w0b, covT, nullptr, sA, sB0, BcatT);
    // M1: Pb = w1[:,512:]·[x2s|x]  (bf16)
    mfma_gemm<1, 1536><<<dim3(832), 256, 0, stream>>>(w1pT, BcatT, nullptr, sA, sB0, Pb);
    // M2: out = relu(bn(w1y[b]·yT + up(Pb)))  (49 tiles: 7,6x7 -> grid 8*8*7 per batch)
    mfma_gemm<2, 512><<<dim3(448, 1, B), 256, 0, stream>>>(w1y, yT, Pb, sA, sB1, out);
}

// Round 8
// 294.434 us; speedup vs baseline: 1.1954x; 1.0440x over previous
//
#include <hip/hip_runtime.h>
#include <math.h>

#define EPSV 1e-5f
#define B 8
#define C 1024
#define C2 512
#define RK 73
#define HW 784      // 28*28
#define QW 3136     // 56*56

typedef __attribute__((ext_vector_type(8))) short bf16x8;
typedef __attribute__((ext_vector_type(4))) float f32x4;

__device__ __forceinline__ unsigned short f2bf(float f) {
    unsigned u = __float_as_uint(f);
    return (unsigned short)((u + 0x7fffu + ((u >> 16) & 1u)) >> 16);
}
__device__ __forceinline__ float ld_f(const float* p) { return *p; }
__device__ __forceinline__ float ld_f(const unsigned short* p) {
    return __uint_as_float(((unsigned)*p) << 16);
}
// 4-wide load -> 4 floats (float4 for f32 src, uint2 of bf16 for ushort src)
__device__ __forceinline__ void ld4f(const float* p, float* d) {
    float4 v = *(const float4*)p;
    d[0] = v.x; d[1] = v.y; d[2] = v.z; d[3] = v.w;
}
__device__ __forceinline__ void ld4f(const unsigned short* p, float* d) {
    uint2 u = *(const uint2*)p;
    d[0] = __uint_as_float((u.x & 0xffffu) << 16);
    d[1] = __uint_as_float(u.x & 0xffff0000u);
    d[2] = __uint_as_float((u.y & 0xffffu) << 16);
    d[3] = __uint_as_float(u.y & 0xffff0000u);
}

// ---------- zero s0 before yT's atomic accumulation ----------
__global__ void zero_s0(float* __restrict__ s0) {
    s0[blockIdx.x * 256 + threadIdx.x] = 0.f;
}

// ---------- SE FC layers (s0 holds raw sums; scale by 1/QW here) ----------
__global__ void se_fc_kernel(const float* __restrict__ s0,
                             const float* __restrict__ fc1_w,
                             const float* __restrict__ fc2_w,
                             float* __restrict__ att) {
    int b = blockIdx.x;
    __shared__ float sv[C2];
    __shared__ float hv[RK];
    for (int i = threadIdx.x; i < C2; i += 256) sv[i] = s0[b * C2 + i] * (1.0f / QW);
    __syncthreads();
    if (threadIdx.x < RK) {
        float acc = 0.f;
        const float4* wr4 = (const float4*)(fc1_w + threadIdx.x * C2);
        const float4* sv4 = (const float4*)sv;
#pragma unroll 16
        for (int k = 0; k < C2 / 4; ++k) {
            float4 w4 = wr4[k], s4 = sv4[k];
            acc += w4.x * s4.x + w4.y * s4.y + w4.z * s4.z + w4.w * s4.w;
        }
        hv[threadIdx.x] = fmaxf(acc, 0.f);
    }
    __syncthreads();
    for (int o = threadIdx.x; o < C2; o += 256) {
        float acc = 0.f;
        const float* wr = fc2_w + o * RK;
#pragma unroll
        for (int j = 0; j < RK; ++j) acc += wr[j] * hv[j];
        att[b * C2 + o] = 1.f / (1.f + expf(-acc));
    }
}

// ---------- depthwise 3x3 conv + row-centered cov -> bf16 ----------
__global__ void dwcov_kernel(const float* __restrict__ x,
                             const float* __restrict__ dw_w,
                             const float* __restrict__ dw_b,
                             unsigned short* __restrict__ cov) {
    int bc = blockIdx.x;
    int c = bc & (C - 1);
    __shared__ float xs[HW];
    __shared__ __align__(16) float x1[HW];
    __shared__ float rm[28];
    const float* px = x + (size_t)bc * HW;
    for (int i = threadIdx.x; i < HW; i += 256) xs[i] = px[i];
    float wk[9];
#pragma unroll
    for (int j = 0; j < 9; ++j) wk[j] = dw_w[c * 9 + j];
    float bias = dw_b[c];
    __syncthreads();
    for (int p = threadIdx.x; p < HW; p += 256) {
        int h = p / 28, w = p - h * 28;
        float acc = bias;
#pragma unroll
        for (int dh = 0; dh < 3; ++dh) {
            int hh = h + dh - 1;
            if (hh < 0 || hh >= 28) continue;
#pragma unroll
            for (int dw = 0; dw < 3; ++dw) {
                int ww = w + dw - 1;
                if (ww < 0 || ww >= 28) continue;
                acc += xs[hh * 28 + ww] * wk[dh * 3 + dw];
            }
        }
        x1[p] = acc;
    }
    __syncthreads();
    if (threadIdx.x < 28) {
        float s = 0.f;
        for (int w = 0; w < 28; ++w) s += x1[threadIdx.x * 28 + w];
        rm[threadIdx.x] = s * (1.f / 28.f);
    }
    __syncthreads();
    unsigned short* pc = cov + (size_t)bc * HW;
    for (int p = threadIdx.x; p < HW; p += 256) {
        int h = p / 28, g = p - h * 28;
        float mh = rm[h], mg = rm[g];
        // float4 LDS reads: 7x2 ds_read_b128 instead of 28x2 scalar (rows are 112B,
        // 16B-aligned). Same FP order as scalar loop (w ascending).
        const float4* xh = (const float4*)&x1[h * 28];
        const float4* xg = (const float4*)&x1[g * 28];
        float acc = 0.f;
#pragma unroll
        for (int w4 = 0; w4 < 7; ++w4) {
            float4 a = xh[w4], bq = xg[w4];
            acc += (a.x - mh) * (bq.x - mg);
            acc += (a.y - mh) * (bq.y - mg);
            acc += (a.z - mh) * (bq.z - mg);
            acc += (a.w - mh) * (bq.w - mg);
        }
        pc[p] = f2bf(acc * (1.f / 27.f));
    }
}

// ---------- pack weights bf16; fold att into per-batch w1y; fold bias+bn ----------
__global__ void pack_w(const float* __restrict__ conv_w, const float* __restrict__ conv_b,
                       const float* __restrict__ conv1_w, const float* __restrict__ conv1_b,
                       const float* __restrict__ bn_g, const float* __restrict__ bn_b,
                       const float* __restrict__ bn_m, const float* __restrict__ bn_v,
                       const float* __restrict__ att,
                       unsigned short* __restrict__ w0b, unsigned short* __restrict__ w1y,
                       unsigned short* __restrict__ w1pT,
                       float* __restrict__ sA, float* __restrict__ sB0, float* __restrict__ sB1) {
    int o = blockIdx.x, t = threadIdx.x;
    // w0b: 1024 elems = 256 threads x float4
    {
        int c4 = t * 4;
        float4 w4 = *(const float4*)&conv_w[(size_t)o * C + c4];
        unsigned short pk[4] = { f2bf(w4.x), f2bf(w4.y), f2bf(w4.z), f2bf(w4.w) };
        *(uint2*)&w0b[(size_t)o * C + c4] = *(uint2*)pk;
    }
    // w1pT: 1536 elems = 384 float4 over 256 threads
#pragma unroll
    for (int i = 0; i < 2; ++i) {
        int e = t + i * 256;
        if (e < 384) {
            int c4 = e * 4;
            float4 w4 = *(const float4*)&conv1_w[(size_t)o * 2048 + 512 + c4];
            unsigned short pk[4] = { f2bf(w4.x), f2bf(w4.y), f2bf(w4.z), f2bf(w4.w) };
            *(uint2*)&w1pT[(size_t)o * 1536 + c4] = *(uint2*)pk;
        }
    }
    // w1y: B*C2 = 4096 elems = 1024 float4 over 256 threads
#pragma unroll
    for (int i = 0; i < 4; ++i) {
        int e = t + i * 256;
        int bb = e >> 7, c4 = (e & 127) * 4;
        float4 w4 = *(const float4*)&conv1_w[(size_t)o * 2048 + c4];
        float4 a4 = *(const float4*)&att[bb * C2 + c4];
        unsigned short pk[4] = { f2bf(w4.x * a4.x), f2bf(w4.y * a4.y),
                                 f2bf(w4.z * a4.z), f2bf(w4.w * a4.w) };
        *(uint2*)&w1y[((size_t)bb * C2 + o) * C2 + c4] = *(uint2*)pk;
    }
    if (t == 0) {
        float sc = rsqrtf(bn_v[o] + EPSV) * bn_g[o];
        float bi = bn_b[o] - bn_m[o] * sc;
        sA[o] = sc;
        sB0[o] = conv_b[o] * sc + bi;
        sB1[o] = conv1_b[o] * sc + bi;
    }
}

// ---------- tiled transpose+convert: src[b][rows][cols] -> dst[(b,col)][dpitch]+doff ----------
// Loads vectorized (float4 / uint2-bf16x4): 16 threads x 4B-elems cover a 64-row; 4 passes.
// Stores vectorized: two short8 (16B) stores per thread.
// GAP: additionally reduce each channel-row's 64 staged values and atomicAdd into
// s0[b*rows + c] (fuses the old gap_kernel's 51.4MB y re-read into this pass).
template<typename ST, bool GAP>
__global__ __launch_bounds__(256)
void transpose_pass(const ST* __restrict__ src, unsigned short* __restrict__ dst,
                    float* __restrict__ s0,
                    int rows, int cols, int dpitch, int doff) {
    int b = blockIdx.z;
    int c0 = blockIdx.y * 64, p0 = blockIdx.x * 64;
    __shared__ float ts[64][65];
    int tid = threadIdx.x;
    int pl4 = (tid & 15) * 4, rr = tid >> 4;
    const ST* sb = src + ((size_t)b * rows + c0) * cols + p0;
    if (p0 + pl4 < cols) {           // cols%4==0 -> full 4-vector valid
#pragma unroll
        for (int j = 0; j < 4; ++j) {
            int cl = rr + j * 16;
            float d[4];
            ld4f(&sb[(size_t)cl * cols + pl4], d);
            ts[cl][pl4 + 0] = d[0]; ts[cl][pl4 + 1] = d[1];
            ts[cl][pl4 + 2] = d[2]; ts[cl][pl4 + 3] = d[3];
        }
    }
    __syncthreads();
    int pl2b = tid >> 3, cl0 = (tid & 7) * 8;
#pragma unroll
    for (int j = 0; j < 2; ++j) {
        int pl2 = pl2b + j * 32;
        if (p0 + pl2 < cols) {
            unsigned short pk[8];
#pragma unroll
            for (int i = 0; i < 8; ++i) pk[i] = f2bf(ts[cl0 + i][pl2]);
            *(uint4*)&dst[((size_t)b * cols + p0 + pl2) * dpitch + doff + c0 + cl0] = *(uint4*)pk;
        }
    }
    if (GAP) {
        if (tid < 64) {
            float s = 0.f;
#pragma unroll
            for (int i = 0; i < 64; ++i) s += ts[tid][i];   // banks (tid*65+i)%32 distinct per tid
            atomicAdd(&s0[b * rows + c0 + tid], s);
        }
    }
}

// ---------- MFMA GEMM: 64o x 64n, BK=32, 4-deep reg prefetch, raw-barrier pipeline ----------
// LDS: unpadded 32-short (64B) rows with XOR swizzle -- 16B chunk c of row r lives at
// r*32 + 8*(c ^ ((r>>1)&3)), same XOR on read. (R5/R7-verified: conflicts 6.5M -> 106K.)
// Pipeline depth 4 (was 2): four register stage-sets; body i computes chunk i from LDS
// buf i&1, STs chunk i+1 (set (i+1)&3, loaded 4 bodies earlier), LDs chunk i+5 into the
// freed set. Load->ds_write lead = 4 bodies (~1200+ cy) > ~900 cy HBM-miss latency, so
// the compiler's counted vmcnt before the ds_write no longer stalls (R7: ~625 cy/step
// measured vs ~190 cy of work = vmcnt-stall-bound at 2-deep). Loads stay in flight
// across raw s_barrier (lgkmcnt-only publish, no vmcnt(0) drain per K-step).
// XCD classes balanced & bijective: NT=49 -> 7,6*7; NT=98 -> 13,13,12*6. XCD = bx%8.
// MODE 0: A=w0b    K=1024, B=covT  [(b,p)][1024]; epi bn+sigmoid -> BcatT cols 0..511
// MODE 1: A=w1pT   K=1536, B=BcatT [(b,p)][1536]; epi f2bf -> Pb [b][o][784]
// MODE 2: A=w1y[b] K=512,  B=yT    [(b,q)][512];  epi (acc+up(Pb))*bn relu -> out
template<int MODE, int K>
__global__ __launch_bounds__(256)
void mfma_gemm(const unsigned short* __restrict__ wpk,
               const unsigned short* __restrict__ bsrc,
               const unsigned short* __restrict__ Pb,
               const float* __restrict__ sA, const float* __restrict__ sB,
               void* __restrict__ outv) {
    constexpr int NIT = K / 32;                  // 32 / 48 / 16 -- all %4==0
    constexpr int NT  = (MODE == 2) ? 49 : 98;   // n-tiles
    constexpr int QN = NT >> 3, REM = NT & 7;
    int bx = blockIdx.x;
    int r = bx & 7, ii = bx >> 3;
    int og = ii & 7, s = ii >> 3;
    int cnt = QN + (r < REM ? 1 : 0);
    if (s >= cnt) return;
    int t = (r < REM ? r * (QN + 1) : REM * (QN + 1) + (r - REM) * QN) + s;
    int o0 = og * 64;
    int n0 = t * 64;
    int b = blockIdx.z;
    union SM {
        struct { __align__(16) unsigned short Wt[2][2048]; __align__(16) unsigned short At[2][2048]; } s;
        float pt[(MODE == 2) ? 64 * 84 : 4];
    };
    __shared__ SM sm;
    int tid = threadIdx.x;
    int lane = tid & 63, wv = tid >> 6;
    int ln = lane & 15, quad = lane >> 4;
    int o_w = (wv >> 1) * 32, q_w = (wv & 1) * 32;
    int swr = tid >> 2, swk = (tid & 3) * 8;   // 16B staging: row, k-off (global)
    int stw = swr * 32 + (((tid & 3) ^ ((swr >> 1) & 3)) << 3);   // swizzled LDS write off
    int rq  = (quad ^ ((ln >> 1) & 3)) << 3;                      // swizzled LDS read chunk
    const unsigned short* wp = (MODE == 2) ? wpk + (size_t)b * C2 * C2 : wpk;
    const unsigned short* wg = wp + (size_t)(o0 + swr) * K + swk;
    const unsigned short* bg = bsrc + ((size_t)((MODE == 2) ? b * QW : 0) + n0 + swr) * K + swk;

    uint4 stA_a, stA_b, stB_a, stB_b, stC_a, stC_b, stD_a, stD_b;  // 4 register stage-sets

#define LD_STAGE(P, CH) {                                                   \
        P##_a = *(const uint4*)(wg + (size_t)(CH) * 32);                    \
        P##_b = *(const uint4*)(bg + (size_t)(CH) * 32); }

#define ST_STAGE(P, BUF) {                                                  \
        *(uint4*)&sm.s.Wt[BUF][stw] = P##_a;                                \
        *(uint4*)&sm.s.At[BUF][stw] = P##_b; }

#define GEMM_BODY(BUF, P, CHW, CHL) {                                               \
        bf16x8 af0 = *(const bf16x8*)&sm.s.Wt[BUF][(o_w + ln) * 32 + rq];           \
        bf16x8 af1 = *(const bf16x8*)&sm.s.Wt[BUF][(o_w + 16 + ln) * 32 + rq];      \
        bf16x8 bf0 = *(const bf16x8*)&sm.s.At[BUF][(q_w + ln) * 32 + rq];           \
        bf16x8 bf1 = *(const bf16x8*)&sm.s.At[BUF][(q_w + 16 + ln) * 32 + rq];      \
        acc[0][0] = __builtin_amdgcn_mfma_f32_16x16x32_bf16(af0, bf0, acc[0][0], 0, 0, 0); \
        acc[0][1] = __builtin_amdgcn_mfma_f32_16x16x32_bf16(af0, bf1, acc[0][1], 0, 0, 0); \
        acc[1][0] = __builtin_amdgcn_mfma_f32_16x16x32_bf16(af1, bf0, acc[1][0], 0, 0, 0); \
        acc[1][1] = __builtin_amdgcn_mfma_f32_16x16x32_bf16(af1, bf1, acc[1][1], 0, 0, 0); \
        if ((CHW) < NIT) {                                                          \
            ST_STAGE(P, (BUF) ^ 1)                                                  \
            if ((CHL) < NIT) LD_STAGE(P, (CHL))                                     \
            asm volatile("s_waitcnt lgkmcnt(0)" ::: "memory");                      \
            __builtin_amdgcn_s_barrier();                                           \
            __builtin_amdgcn_sched_barrier(0);                                      \
        } }

    // prologue: chunk0 -> LDS[0]; chunks 1..4 in flight across the barrier
    LD_STAGE(stA, 0)
    ST_STAGE(stA, 0)
    LD_STAGE(stB, 1)
    LD_STAGE(stC, 2)
    LD_STAGE(stD, 3)
    LD_STAGE(stA, 4)
    asm volatile("s_waitcnt lgkmcnt(0)" ::: "memory");
    __builtin_amdgcn_s_barrier();
    __builtin_amdgcn_sched_barrier(0);

    f32x4 acc[2][2] = {};
    for (int i2 = 0; i2 < NIT; i2 += 4) {
        GEMM_BODY(0, stB, i2 + 1, i2 + 5)
        GEMM_BODY(1, stC, i2 + 2, i2 + 6)
        GEMM_BODY(0, stD, i2 + 3, i2 + 7)
        GEMM_BODY(1, stA, i2 + 4, i2 + 8)
    }
#undef GEMM_BODY
#undef ST_STAGE
#undef LD_STAGE

    // ---- epilogue; D: row = quad*4+reg, col = ln ----
    if (MODE == 2) {
        float* outp = (float*)outv;
        int h0 = n0 / 56;
        int hmin = (h0 & 1) ? (h0 >> 1) : max(0, (h0 >> 1) - 1);
        // batched Pb staging: 21 independent loads in flight, then publish to LDS.
        float stv[21];
#pragma unroll
        for (int j = 0; j < 21; ++j) {
            int e = tid + j * 256;               // 21*256 == 64*84 exactly
            int o_l = e / 84, rem = e - o_l * 84;
            int s2 = rem / 28, w = rem - s2 * 28;
            int row = min(hmin + s2, 27);
            stv[j] = ld_f(&Pb[((size_t)b * C2 + o0 + o_l) * HW + row * 28 + w]);
        }
        __syncthreads();                          // all waves done with K-loop LDS
#pragma unroll
        for (int j = 0; j < 21; ++j) sm.pt[tid + j * 256] = stv[j];
        __syncthreads();
#pragma unroll
        for (int nt = 0; nt < 2; ++nt) {
            int q = n0 + q_w + nt * 16 + ln;
            int hq = q / 56, wq = q - hq * 56;
            int hm = hq >> 1, wm = wq >> 1;
            int hn = (hq & 1) ? min(hm + 1, 27) : max(hm - 1, 0);
            int wn_ = (wq & 1) ? min(wm + 1, 27) : max(wm - 1, 0);
            int rm_ = (hm - hmin) * 28, rn_ = (hn - hmin) * 28;
#pragma unroll
            for (int mt = 0; mt < 2; ++mt)
#pragma unroll
                for (int reg = 0; reg < 4; ++reg) {
                    int ol = o_w + mt * 16 + quad * 4 + reg;
                    int o = o0 + ol;
                    const float* Pt = &sm.pt[ol * 84];
                    float up = 0.5625f * Pt[rm_ + wm] + 0.1875f * (Pt[rm_ + wn_] + Pt[rn_ + wm])
                             + 0.0625f * Pt[rn_ + wn_];
                    float v = (acc[mt][nt][reg] + up) * sA[o] + sB[o];
                    outp[((size_t)b * C2 + o) * QW + q] = fmaxf(v, 0.f);
                }
        }
    } else if (MODE == 0) {
        unsigned short* outp = (unsigned short*)outv;   // BcatT, pitch 1536, cols 0..511
#pragma unroll
        for (int nt = 0; nt < 2; ++nt) {
            int n = n0 + q_w + nt * 16 + ln;
#pragma unroll
            for (int mt = 0; mt < 2; ++mt) {
                int ob = o0 + o_w + mt * 16 + quad * 4;
                unsigned short pk[4];
#pragma unroll
                for (int reg = 0; reg < 4; ++reg) {
                    int o = ob + reg;
                    float v = acc[mt][nt][reg] * sA[o] + sB[o];
                    pk[reg] = f2bf(1.f / (1.f + expf(-v)));
                }
                *(uint2*)&outp[(size_t)n * 1536 + ob] = *(uint2*)pk;
            }
        }
    } else {
        unsigned short* outp = (unsigned short*)outv;   // Pb [b][o][784] bf16
#pragma unroll
        for (int nt = 0; nt < 2; ++nt) {
            int n = n0 + q_w + nt * 16 + ln;
            int be = n / HW, pe = n - be * HW;
#pragma unroll
            for (int mt = 0; mt < 2; ++mt)
#pragma unroll
                for (int reg = 0; reg < 4; ++reg) {
                    int o = o0 + o_w + mt * 16 + quad * 4 + reg;
                    outp[((size_t)be * C2 + o) * HW + pe] = f2bf(acc[mt][nt][reg]);
                }
        }
    }
}

extern "C" void kernel_launch(void* const* d_in, const int* in_sizes, int n_in,
                              void* d_out, int out_size, void* d_ws, size_t ws_size,
                              hipStream_t stream) {
    const float* y       = (const float*)d_in[0];
    const float* x       = (const float*)d_in[1];
    const float* fc1_w   = (const float*)d_in[2];
    const float* fc2_w   = (const float*)d_in[3];
    const float* conv_w  = (const float*)d_in[4];
    const float* conv_b  = (const float*)d_in[5];
    const float* conv1_w = (const float*)d_in[6];
    const float* conv1_b = (const float*)d_in[7];
    const float* bn_g    = (const float*)d_in[8];
    const float* bn_b    = (const float*)d_in[9];
    const float* bn_m    = (const float*)d_in[10];
    const float* bn_v    = (const float*)d_in[11];
    const float* dw_w    = (const float*)d_in[12];
    const float* dw_b    = (const float*)d_in[13];
    float* out = (float*)d_out;

    // ---- d_out doubles as scratch for buffers that die before M2's epilogue ----
    // cov_bf(12.85M) + covT(12.85M) + BcatT(19.27M) = 44,957,696 B <= out 51,380,224 B.
    // M2 writes every out element (o: 8x64 tiles, q: 49x64 tiles exact) -> full overwrite.
    unsigned short* cov_bf = (unsigned short*)d_out;         // 8*1024*784
    unsigned short* covT   = cov_bf + (size_t)B * C * HW;    // 8*784*1024
    unsigned short* BcatT  = covT + (size_t)B * HW * C;      // 6272*1536

    // ---- ws carve: 39,491,584 B (< Round-2-proven 45,389,824 extent) ----
    float* ws  = (float*)d_ws;
    float* s0  = ws;                 // 4096
    float* att = ws + 4096;          // 4096
    float* sA  = ws + 8192;          // 512
    float* sB0 = ws + 8704;          // 512
    float* sB1 = ws + 9216;          // 512 -> header ends at float 9728 (byte 38912, 16B-aligned)
    unsigned short* w0b  = (unsigned short*)(ws + 9728);     // 512*1024 sh
    unsigned short* w1y  = w0b + (size_t)C2 * C;             // 8*512*512 sh
    unsigned short* w1pT = w1y + (size_t)B * C2 * C2;        // 512*1536 sh
    unsigned short* yT   = w1pT + (size_t)C2 * 1536;         // 8*3136*512 sh
    unsigned short* Pb   = yT + (size_t)B * QW * C2;         // 8*512*784 sh

    // gap fused into yT: zero s0, transpose y (read ONCE) with atomic channel sums
    zero_s0<<<16, 256, 0, stream>>>(s0);
    transpose_pass<float, true><<<dim3(49, 8, B), 256, 0, stream>>>(
        y, yT, s0, C2, QW, C2, 0);
    se_fc_kernel<<<B, 256, 0, stream>>>(s0, fc1_w, fc2_w, att);
    pack_w<<<C2, 256, 0, stream>>>(conv_w, conv_b, conv1_w, conv1_b,
                                   bn_g, bn_b, bn_m, bn_v, att,
                                   w0b, w1y, w1pT, sA, sB0, sB1);
    dwcov_kernel<<<B * C, 256, 0, stream>>>(x, dw_w, dw_b, cov_bf);
    // xT: x[b][c][p] -> BcatT[(b,p)][512+c]
    transpose_pass<float, false><<<dim3(13, 16, B), 256, 0, stream>>>(
        x, BcatT, nullptr, C, HW, 1536, 512);
    // covT: cov[b][c][p] -> covT[(b,p)][c]
    transpose_pass<unsigned short, false><<<dim3(13, 16, B), 256, 0, stream>>>(
        cov_bf, covT, nullptr, C, HW, C, 0);
    // M0: x2s = sigmoid(bn(conv(cov))) -> BcatT cols 0..511  (98 tiles: 13,13,12x6 -> grid 8*8*13)
    mfma_gemm<0, 1024><<<dim3(832), 256, 0, stream>>>(w0b, covT, nullptr, sA, sB0, BcatT);
    // M1: Pb = w1[:,512:]·[x2s|x]  (bf16)
    mfma_gemm<1, 1536><<<dim3(832), 256, 0, stream>>>(w1pT, BcatT, nullptr, sA, sB0, Pb);
    // M2: out = relu(bn(w1y[b]·yT + up(Pb)))  (49 tiles: 7,6x7 -> grid 8*8*7 per batch)
    mfma_gemm<2, 512><<<dim3(448, 1, B), 256, 0, stream>>>(w1y, yT, Pb, sA, sB1, out);
}

// Round 9
// 284.803 us; speedup vs baseline: 1.2358x; 1.0338x over previous
//
#include <hip/hip_runtime.h>
#include <math.h>

#define EPSV 1e-5f
#define B 8
#define C 1024
#define C2 512
#define RK 73
#define HW 784      // 28*28
#define QW 3136     // 56*56

typedef __attribute__((ext_vector_type(8))) short bf16x8;
typedef __attribute__((ext_vector_type(4))) float f32x4;

__device__ __forceinline__ unsigned short f2bf(float f) {
    unsigned u = __float_as_uint(f);
    return (unsigned short)((u + 0x7fffu + ((u >> 16) & 1u)) >> 16);
}
__device__ __forceinline__ float ld_f(const float* p) { return *p; }
__device__ __forceinline__ float ld_f(const unsigned short* p) {
    return __uint_as_float(((unsigned)*p) << 16);
}
// 4-wide load -> 4 floats (float4 for f32 src, uint2 of bf16 for ushort src)
__device__ __forceinline__ void ld4f(const float* p, float* d) {
    float4 v = *(const float4*)p;
    d[0] = v.x; d[1] = v.y; d[2] = v.z; d[3] = v.w;
}
__device__ __forceinline__ void ld4f(const unsigned short* p, float* d) {
    uint2 u = *(const uint2*)p;
    d[0] = __uint_as_float((u.x & 0xffffu) << 16);
    d[1] = __uint_as_float(u.x & 0xffff0000u);
    d[2] = __uint_as_float((u.y & 0xffffu) << 16);
    d[3] = __uint_as_float(u.y & 0xffff0000u);
}

// ---------- zero s0 before yT's atomic accumulation ----------
__global__ void zero_s0(float* __restrict__ s0) {
    s0[blockIdx.x * 256 + threadIdx.x] = 0.f;
}

// ---------- SE FC layers (s0 holds raw sums; scale by 1/QW here) ----------
__global__ void se_fc_kernel(const float* __restrict__ s0,
                             const float* __restrict__ fc1_w,
                             const float* __restrict__ fc2_w,
                             float* __restrict__ att) {
    int b = blockIdx.x;
    __shared__ float sv[C2];
    __shared__ float hv[RK];
    for (int i = threadIdx.x; i < C2; i += 256) sv[i] = s0[b * C2 + i] * (1.0f / QW);
    __syncthreads();
    if (threadIdx.x < RK) {
        float acc = 0.f;
        const float4* wr4 = (const float4*)(fc1_w + threadIdx.x * C2);
        const float4* sv4 = (const float4*)sv;
#pragma unroll 16
        for (int k = 0; k < C2 / 4; ++k) {
            float4 w4 = wr4[k], s4 = sv4[k];
            acc += w4.x * s4.x + w4.y * s4.y + w4.z * s4.z + w4.w * s4.w;
        }
        hv[threadIdx.x] = fmaxf(acc, 0.f);
    }
    __syncthreads();
    for (int o = threadIdx.x; o < C2; o += 256) {
        float acc = 0.f;
        const float* wr = fc2_w + o * RK;
#pragma unroll
        for (int j = 0; j < RK; ++j) acc += wr[j] * hv[j];
        att[b * C2 + o] = 1.f / (1.f + expf(-acc));
    }
}

// ---------- depthwise 3x3 conv + row-centered cov -> bf16 ----------
// cov[h][g] == cov[g][h] BITWISE (same products, same w-order), so compute only the
// 406 lower-triangle pairs and mirror-store -- halves the dominant 28-MAC loop.
__global__ void dwcov_kernel(const float* __restrict__ x,
                             const float* __restrict__ dw_w,
                             const float* __restrict__ dw_b,
                             unsigned short* __restrict__ cov) {
    int bc = blockIdx.x;
    int c = bc & (C - 1);
    __shared__ float xs[HW];
    __shared__ __align__(16) float x1[HW];
    __shared__ float rm[28];
    const float* px = x + (size_t)bc * HW;
    for (int i = threadIdx.x; i < HW; i += 256) xs[i] = px[i];
    float wk[9];
#pragma unroll
    for (int j = 0; j < 9; ++j) wk[j] = dw_w[c * 9 + j];
    float bias = dw_b[c];
    __syncthreads();
    for (int p = threadIdx.x; p < HW; p += 256) {
        int h = p / 28, w = p - h * 28;
        float acc = bias;
#pragma unroll
        for (int dh = 0; dh < 3; ++dh) {
            int hh = h + dh - 1;
            if (hh < 0 || hh >= 28) continue;
#pragma unroll
            for (int dw = 0; dw < 3; ++dw) {
                int ww = w + dw - 1;
                if (ww < 0 || ww >= 28) continue;
                acc += xs[hh * 28 + ww] * wk[dh * 3 + dw];
            }
        }
        x1[p] = acc;
    }
    __syncthreads();
    if (threadIdx.x < 28) {
        float s = 0.f;
        for (int w = 0; w < 28; ++w) s += x1[threadIdx.x * 28 + w];
        rm[threadIdx.x] = s * (1.f / 28.f);
    }
    __syncthreads();
    unsigned short* pc = cov + (size_t)bc * HW;
    for (int idx = threadIdx.x; idx < 406; idx += 256) {     // 406 = 28*29/2
        int h = (int)((sqrtf((float)(8 * idx + 1)) - 1.f) * 0.5f);
        while ((h + 1) * (h + 2) / 2 <= idx) ++h;
        while (h * (h + 1) / 2 > idx) --h;
        int g = idx - h * (h + 1) / 2;                       // g <= h
        float mh = rm[h], mg = rm[g];
        const float4* xh = (const float4*)&x1[h * 28];
        const float4* xg = (const float4*)&x1[g * 28];
        float acc = 0.f;
#pragma unroll
        for (int w4 = 0; w4 < 7; ++w4) {
            float4 a = xh[w4], bq = xg[w4];
            acc += (a.x - mh) * (bq.x - mg);
            acc += (a.y - mh) * (bq.y - mg);
            acc += (a.z - mh) * (bq.z - mg);
            acc += (a.w - mh) * (bq.w - mg);
        }
        unsigned short v = f2bf(acc * (1.f / 27.f));
        pc[h * 28 + g] = v;
        pc[g * 28 + h] = v;
    }
}

// ---------- pack weights bf16; fold att into per-batch w1y; fold bias+bn ----------
__global__ void pack_w(const float* __restrict__ conv_w, const float* __restrict__ conv_b,
                       const float* __restrict__ conv1_w, const float* __restrict__ conv1_b,
                       const float* __restrict__ bn_g, const float* __restrict__ bn_b,
                       const float* __restrict__ bn_m, const float* __restrict__ bn_v,
                       const float* __restrict__ att,
                       unsigned short* __restrict__ w0b, unsigned short* __restrict__ w1y,
                       unsigned short* __restrict__ w1pT,
                       float* __restrict__ sA, float* __restrict__ sB0, float* __restrict__ sB1) {
    int o = blockIdx.x, t = threadIdx.x;
    // w0b: 1024 elems = 256 threads x float4
    {
        int c4 = t * 4;
        float4 w4 = *(const float4*)&conv_w[(size_t)o * C + c4];
        unsigned short pk[4] = { f2bf(w4.x), f2bf(w4.y), f2bf(w4.z), f2bf(w4.w) };
        *(uint2*)&w0b[(size_t)o * C + c4] = *(uint2*)pk;
    }
    // w1pT: 1536 elems = 384 float4 over 256 threads
#pragma unroll
    for (int i = 0; i < 2; ++i) {
        int e = t + i * 256;
        if (e < 384) {
            int c4 = e * 4;
            float4 w4 = *(const float4*)&conv1_w[(size_t)o * 2048 + 512 + c4];
            unsigned short pk[4] = { f2bf(w4.x), f2bf(w4.y), f2bf(w4.z), f2bf(w4.w) };
            *(uint2*)&w1pT[(size_t)o * 1536 + c4] = *(uint2*)pk;
        }
    }
    // w1y: B*C2 = 4096 elems = 1024 float4 over 256 threads
#pragma unroll
    for (int i = 0; i < 4; ++i) {
        int e = t + i * 256;
        int bb = e >> 7, c4 = (e & 127) * 4;
        float4 w4 = *(const float4*)&conv1_w[(size_t)o * 2048 + c4];
        float4 a4 = *(const float4*)&att[bb * C2 + c4];
        unsigned short pk[4] = { f2bf(w4.x * a4.x), f2bf(w4.y * a4.y),
                                 f2bf(w4.z * a4.z), f2bf(w4.w * a4.w) };
        *(uint2*)&w1y[((size_t)bb * C2 + o) * C2 + c4] = *(uint2*)pk;
    }
    if (t == 0) {
        float sc = rsqrtf(bn_v[o] + EPSV) * bn_g[o];
        float bi = bn_b[o] - bn_m[o] * sc;
        sA[o] = sc;
        sB0[o] = conv_b[o] * sc + bi;
        sB1[o] = conv1_b[o] * sc + bi;
    }
}

// ---------- tiled transpose+convert: src[b][rows][cols] -> dst[(b,col)][dpitch]+doff ----------
// Loads vectorized (float4 / uint2-bf16x4); stores two short8 (16B) per thread.
// GAP: additionally reduce each channel-row's 64 staged values and atomicAdd into
// s0[b*rows + c] (fuses the old gap_kernel's 51.4MB y re-read into this pass).
template<typename ST, bool GAP>
__global__ __launch_bounds__(256)
void transpose_pass(const ST* __restrict__ src, unsigned short* __restrict__ dst,
                    float* __restrict__ s0,
                    int rows, int cols, int dpitch, int doff) {
    int b = blockIdx.z;
    int c0 = blockIdx.y * 64, p0 = blockIdx.x * 64;
    __shared__ float ts[64][65];
    int tid = threadIdx.x;
    int pl4 = (tid & 15) * 4, rr = tid >> 4;
    const ST* sb = src + ((size_t)b * rows + c0) * cols + p0;
    if (p0 + pl4 < cols) {           // cols%4==0 -> full 4-vector valid
#pragma unroll
        for (int j = 0; j < 4; ++j) {
            int cl = rr + j * 16;
            float d[4];
            ld4f(&sb[(size_t)cl * cols + pl4], d);
            ts[cl][pl4 + 0] = d[0]; ts[cl][pl4 + 1] = d[1];
            ts[cl][pl4 + 2] = d[2]; ts[cl][pl4 + 3] = d[3];
        }
    }
    __syncthreads();
    int pl2b = tid >> 3, cl0 = (tid & 7) * 8;
#pragma unroll
    for (int j = 0; j < 2; ++j) {
        int pl2 = pl2b + j * 32;
        if (p0 + pl2 < cols) {
            unsigned short pk[8];
#pragma unroll
            for (int i = 0; i < 8; ++i) pk[i] = f2bf(ts[cl0 + i][pl2]);
            *(uint4*)&dst[((size_t)b * cols + p0 + pl2) * dpitch + doff + c0 + cl0] = *(uint4*)pk;
        }
    }
    if (GAP) {
        if (tid < 64) {
            float s = 0.f;
#pragma unroll
            for (int i = 0; i < 64; ++i) s += ts[tid][i];   // banks (tid*65+i)%32 distinct per tid
            atomicAdd(&s0[b * rows + c0 + tid], s);
        }
    }
}

// ---------- MFMA GEMM: 64o x 64n, BK=64 bodies, 4-deep reg prefetch ----------
// BK=64 (was 32): 8 MFMA + 8 ds_read_b128 per {publish, lgkmcnt, barrier} round --
// HALF the sync events per K-element (R8: ~550cy/body vs ~190cy work = sync-bound).
// LDS rows are 128B (full bank wrap -> bank depends on slot only), so swizzle spreads
// by ROW: 16B chunk c (0..7) of row r lives at r*64 + 8*(c^(r&7)) shorts, same XOR on
// read. Reads: 8-lane groups = 8 consecutive rows, slots c^(r&7) all distinct -> 0-way.
// Writes: thread (r=tid>>2, cq=tid&3) stores chunks 2cq,2cq+1; an 8-lane group covers
// slots {0..7} exactly -> 0-way. Global loads stay 128B-contiguous per 4-lane group.
// Pipeline: 4 register stage-sets, lead = 4 bodies = 256 K-elems (~1600cy >> 900cy HBM
// latency); loads in flight across raw s_barrier (lgkmcnt-only publish, no vmcnt(0)).
// XCD classes balanced & bijective: NT=49 -> 7,6*7; NT=98 -> 13,13,12*6. XCD = bx%8.
// MODE 0: A=w0b    K=1024, B=covT  [(b,p)][1024]; epi bn+sigmoid -> BcatT cols 0..511
// MODE 1: A=w1pT   K=1536, B=BcatT [(b,p)][1536]; epi f2bf -> Pb [b][o][784]
// MODE 2: A=w1y[b] K=512,  B=yT    [(b,q)][512];  epi (acc+up(Pb))*bn relu -> out
template<int MODE, int K>
__global__ __launch_bounds__(256)
void mfma_gemm(const unsigned short* __restrict__ wpk,
               const unsigned short* __restrict__ bsrc,
               const unsigned short* __restrict__ Pb,
               const float* __restrict__ sA, const float* __restrict__ sB,
               void* __restrict__ outv) {
    constexpr int NIT = K / 64;                  // 16 / 24 / 8 -- all %4==0
    constexpr int NT  = (MODE == 2) ? 49 : 98;   // n-tiles
    constexpr int QN = NT >> 3, REM = NT & 7;
    int bx = blockIdx.x;
    int r = bx & 7, ii = bx >> 3;
    int og = ii & 7, s = ii >> 3;
    int cnt = QN + (r < REM ? 1 : 0);
    if (s >= cnt) return;
    int t = (r < REM ? r * (QN + 1) : REM * (QN + 1) + (r - REM) * QN) + s;
    int o0 = og * 64;
    int n0 = t * 64;
    int b = blockIdx.z;
    union SM {
        struct { __align__(16) unsigned short Wt[2][4096]; __align__(16) unsigned short At[2][4096]; } s;
        float pt[(MODE == 2) ? 64 * 84 : 4];
    };
    __shared__ SM sm;
    int tid = threadIdx.x;
    int lane = tid & 63, wv = tid >> 6;
    int ln = lane & 15, quad = lane >> 4;
    int o_w = (wv >> 1) * 32, q_w = (wv & 1) * 32;
    int r_ = tid >> 2, cq = tid & 3;             // staging: row, 32B column pair
    int stw0 = r_ * 64 + ((( cq << 1)      ^ (r_ & 7)) << 3);   // swizzled write offs
    int stw1 = r_ * 64 + ((((cq << 1) | 1) ^ (r_ & 7)) << 3);
    int rq0 = (( quad      ^ (ln & 7)) << 3);    // swizzled read chunk, kk=0
    int rq1 = (((4 | quad) ^ (ln & 7)) << 3);    // kk=1
    const unsigned short* wp = (MODE == 2) ? wpk + (size_t)b * C2 * C2 : wpk;
    const unsigned short* wg = wp + (size_t)(o0 + r_) * K + cq * 16;
    const unsigned short* bg = bsrc + ((size_t)((MODE == 2) ? b * QW : 0) + n0 + r_) * K + cq * 16;

    uint4 stA_a0, stA_a1, stA_b0, stA_b1;        // 4 register stage-sets (A,B x 2 uint4)
    uint4 stB_a0, stB_a1, stB_b0, stB_b1;
    uint4 stC_a0, stC_a1, stC_b0, stC_b1;
    uint4 stD_a0, stD_a1, stD_b0, stD_b1;

#define LD_STAGE(P, CH) {                                                   \
        P##_a0 = *(const uint4*)(wg + (size_t)(CH) * 64);                   \
        P##_a1 = *(const uint4*)(wg + (size_t)(CH) * 64 + 8);               \
        P##_b0 = *(const uint4*)(bg + (size_t)(CH) * 64);                   \
        P##_b1 = *(const uint4*)(bg + (size_t)(CH) * 64 + 8); }

#define ST_STAGE(P, BUF) {                                                  \
        *(uint4*)&sm.s.Wt[BUF][stw0] = P##_a0;                              \
        *(uint4*)&sm.s.Wt[BUF][stw1] = P##_a1;                              \
        *(uint4*)&sm.s.At[BUF][stw0] = P##_b0;                              \
        *(uint4*)&sm.s.At[BUF][stw1] = P##_b1; }

#define GEMM_BODY(BUF, P, CHW, CHL) {                                               \
        bf16x8 a0 = *(const bf16x8*)&sm.s.Wt[BUF][(o_w + ln) * 64 + rq0];           \
        bf16x8 a1 = *(const bf16x8*)&sm.s.Wt[BUF][(o_w + 16 + ln) * 64 + rq0];      \
        bf16x8 b0 = *(const bf16x8*)&sm.s.At[BUF][(q_w + ln) * 64 + rq0];           \
        bf16x8 b1 = *(const bf16x8*)&sm.s.At[BUF][(q_w + 16 + ln) * 64 + rq0];      \
        bf16x8 a2 = *(const bf16x8*)&sm.s.Wt[BUF][(o_w + ln) * 64 + rq1];           \
        bf16x8 a3 = *(const bf16x8*)&sm.s.Wt[BUF][(o_w + 16 + ln) * 64 + rq1];      \
        bf16x8 b2 = *(const bf16x8*)&sm.s.At[BUF][(q_w + ln) * 64 + rq1];           \
        bf16x8 b3 = *(const bf16x8*)&sm.s.At[BUF][(q_w + 16 + ln) * 64 + rq1];      \
        acc[0][0] = __builtin_amdgcn_mfma_f32_16x16x32_bf16(a0, b0, acc[0][0], 0, 0, 0); \
        acc[0][1] = __builtin_amdgcn_mfma_f32_16x16x32_bf16(a0, b1, acc[0][1], 0, 0, 0); \
        acc[1][0] = __builtin_amdgcn_mfma_f32_16x16x32_bf16(a1, b0, acc[1][0], 0, 0, 0); \
        acc[1][1] = __builtin_amdgcn_mfma_f32_16x16x32_bf16(a1, b1, acc[1][1], 0, 0, 0); \
        acc[0][0] = __builtin_amdgcn_mfma_f32_16x16x32_bf16(a2, b2, acc[0][0], 0, 0, 0); \
        acc[0][1] = __builtin_amdgcn_mfma_f32_16x16x32_bf16(a2, b3, acc[0][1], 0, 0, 0); \
        acc[1][0] = __builtin_amdgcn_mfma_f32_16x16x32_bf16(a3, b2, acc[1][0], 0, 0, 0); \
        acc[1][1] = __builtin_amdgcn_mfma_f32_16x16x32_bf16(a3, b3, acc[1][1], 0, 0, 0); \
        if ((CHW) < NIT) {                                                          \
            ST_STAGE(P, (BUF) ^ 1)                                                  \
            if ((CHL) < NIT) LD_STAGE(P, (CHL))                                     \
            asm volatile("s_waitcnt lgkmcnt(0)" ::: "memory");                      \
            __builtin_amdgcn_s_barrier();                                           \
            __builtin_amdgcn_sched_barrier(0);                                      \
        } }

    // prologue: chunk0 -> LDS[0]; chunks 1..4 in flight across the barrier
    LD_STAGE(stA, 0)
    ST_STAGE(stA, 0)
    LD_STAGE(stB, 1)
    LD_STAGE(stC, 2)
    LD_STAGE(stD, 3)
    LD_STAGE(stA, 4)
    asm volatile("s_waitcnt lgkmcnt(0)" ::: "memory");
    __builtin_amdgcn_s_barrier();
    __builtin_amdgcn_sched_barrier(0);

    f32x4 acc[2][2] = {};
    for (int i2 = 0; i2 < NIT; i2 += 4) {
        GEMM_BODY(0, stB, i2 + 1, i2 + 5)
        GEMM_BODY(1, stC, i2 + 2, i2 + 6)
        GEMM_BODY(0, stD, i2 + 3, i2 + 7)
        GEMM_BODY(1, stA, i2 + 4, i2 + 8)
    }
#undef GEMM_BODY
#undef ST_STAGE
#undef LD_STAGE

    // ---- epilogue; D: row = quad*4+reg, col = ln ----
    if (MODE == 2) {
        float* outp = (float*)outv;
        int h0 = n0 / 56;
        int hmin = (h0 & 1) ? (h0 >> 1) : max(0, (h0 >> 1) - 1);
        // batched Pb staging: 21 independent loads in flight, then publish to LDS.
        float stv[21];
#pragma unroll
        for (int j = 0; j < 21; ++j) {
            int e = tid + j * 256;               // 21*256 == 64*84 exactly
            int o_l = e / 84, rem = e - o_l * 84;
            int s2 = rem / 28, w = rem - s2 * 28;
            int row = min(hmin + s2, 27);
            stv[j] = ld_f(&Pb[((size_t)b * C2 + o0 + o_l) * HW + row * 28 + w]);
        }
        __syncthreads();                          // all waves done with K-loop LDS
#pragma unroll
        for (int j = 0; j < 21; ++j) sm.pt[tid + j * 256] = stv[j];
        __syncthreads();
#pragma unroll
        for (int nt = 0; nt < 2; ++nt) {
            int q = n0 + q_w + nt * 16 + ln;
            int hq = q / 56, wq = q - hq * 56;
            int hm = hq >> 1, wm = wq >> 1;
            int hn = (hq & 1) ? min(hm + 1, 27) : max(hm - 1, 0);
            int wn_ = (wq & 1) ? min(wm + 1, 27) : max(wm - 1, 0);
            int rm_ = (hm - hmin) * 28, rn_ = (hn - hmin) * 28;
#pragma unroll
            for (int mt = 0; mt < 2; ++mt)
#pragma unroll
                for (int reg = 0; reg < 4; ++reg) {
                    int ol = o_w + mt * 16 + quad * 4 + reg;
                    int o = o0 + ol;
                    const float* Pt = &sm.pt[ol * 84];
                    float up = 0.5625f * Pt[rm_ + wm] + 0.1875f * (Pt[rm_ + wn_] + Pt[rn_ + wm])
                             + 0.0625f * Pt[rn_ + wn_];
                    float v = (acc[mt][nt][reg] + up) * sA[o] + sB[o];
                    outp[((size_t)b * C2 + o) * QW + q] = fmaxf(v, 0.f);
                }
        }
    } else if (MODE == 0) {
        unsigned short* outp = (unsigned short*)outv;   // BcatT, pitch 1536, cols 0..511
#pragma unroll
        for (int nt = 0; nt < 2; ++nt) {
            int n = n0 + q_w + nt * 16 + ln;
#pragma unroll
            for (int mt = 0; mt < 2; ++mt) {
                int ob = o0 + o_w + mt * 16 + quad * 4;
                unsigned short pk[4];
#pragma unroll
                for (int reg = 0; reg < 4; ++reg) {
                    int o = ob + reg;
                    float v = acc[mt][nt][reg] * sA[o] + sB[o];
                    pk[reg] = f2bf(1.f / (1.f + expf(-v)));
                }
                *(uint2*)&outp[(size_t)n * 1536 + ob] = *(uint2*)pk;
            }
        }
    } else {
        unsigned short* outp = (unsigned short*)outv;   // Pb [b][o][784] bf16
#pragma unroll
        for (int nt = 0; nt < 2; ++nt) {
            int n = n0 + q_w + nt * 16 + ln;
            int be = n / HW, pe = n - be * HW;
#pragma unroll
            for (int mt = 0; mt < 2; ++mt)
#pragma unroll
                for (int reg = 0; reg < 4; ++reg) {
                    int o = o0 + o_w + mt * 16 + quad * 4 + reg;
                    outp[((size_t)be * C2 + o) * HW + pe] = f2bf(acc[mt][nt][reg]);
                }
        }
    }
}

extern "C" void kernel_launch(void* const* d_in, const int* in_sizes, int n_in,
                              void* d_out, int out_size, void* d_ws, size_t ws_size,
                              hipStream_t stream) {
    const float* y       = (const float*)d_in[0];
    const float* x       = (const float*)d_in[1];
    const float* fc1_w   = (const float*)d_in[2];
    const float* fc2_w   = (const float*)d_in[3];
    const float* conv_w  = (const float*)d_in[4];
    const float* conv_b  = (const float*)d_in[5];
    const float* conv1_w = (const float*)d_in[6];
    const float* conv1_b = (const float*)d_in[7];
    const float* bn_g    = (const float*)d_in[8];
    const float* bn_b    = (const float*)d_in[9];
    const float* bn_m    = (const float*)d_in[10];
    const float* bn_v    = (const float*)d_in[11];
    const float* dw_w    = (const float*)d_in[12];
    const float* dw_b    = (const float*)d_in[13];
    float* out = (float*)d_out;

    // ---- d_out doubles as scratch for buffers that die before M2's epilogue ----
    // cov_bf(12.85M) + covT(12.85M) + BcatT(19.27M) = 44,957,696 B <= out 51,380,224 B.
    // M2 writes every out element (o: 8x64 tiles, q: 49x64 tiles exact) -> full overwrite.
    unsigned short* cov_bf = (unsigned short*)d_out;         // 8*1024*784
    unsigned short* covT   = cov_bf + (size_t)B * C * HW;    // 8*784*1024
    unsigned short* BcatT  = covT + (size_t)B * HW * C;      // 6272*1536

    // ---- ws carve: 39,491,584 B (< Round-2-proven 45,389,824 extent) ----
    float* ws  = (float*)d_ws;
    float* s0  = ws;                 // 4096
    float* att = ws + 4096;          // 4096
    float* sA  = ws + 8192;          // 512
    float* sB0 = ws + 8704;          // 512
    float* sB1 = ws + 9216;          // 512 -> header ends at float 9728 (byte 38912, 16B-aligned)
    unsigned short* w0b  = (unsigned short*)(ws + 9728);     // 512*1024 sh
    unsigned short* w1y  = w0b + (size_t)C2 * C;             // 8*512*512 sh
    unsigned short* w1pT = w1y + (size_t)B * C2 * C2;        // 512*1536 sh
    unsigned short* yT   = w1pT + (size_t)C2 * 1536;         // 8*3136*512 sh
    unsigned short* Pb   = yT + (size_t)B * QW * C2;         // 8*512*784 sh

    // gap fused into yT: zero s0, transpose y (read ONCE) with atomic channel sums
    zero_s0<<<16, 256, 0, stream>>>(s0);
    transpose_pass<float, true><<<dim3(49, 8, B), 256, 0, stream>>>(
        y, yT, s0, C2, QW, C2, 0);
    se_fc_kernel<<<B, 256, 0, stream>>>(s0, fc1_w, fc2_w, att);
    pack_w<<<C2, 256, 0, stream>>>(conv_w, conv_b, conv1_w, conv1_b,
                                   bn_g, bn_b, bn_m, bn_v, att,
                                   w0b, w1y, w1pT, sA, sB0, sB1);
    dwcov_kernel<<<B * C, 256, 0, stream>>>(x, dw_w, dw_b, cov_bf);
    // xT: x[b][c][p] -> BcatT[(b,p)][512+c]
    transpose_pass<float, false><<<dim3(13, 16, B), 256, 0, stream>>>(
        x, BcatT, nullptr, C, HW, 1536, 512);
    // covT: cov[b][c][p] -> covT[(b,p)][c]
    transpose_pass<unsigned short, false><<<dim3(13, 16, B), 256, 0, stream>>>(
        cov_bf, covT, nullptr, C, HW, C, 0);
    // M0: x2s = sigmoid(bn(conv(cov))) -> BcatT cols 0..511  (98 tiles: 13,13,12x6 -> grid 8*8*13)
    mfma_gemm<0, 1024><<<dim3(832), 256, 0, stream>>>(w0b, covT, nullptr, sA, sB0, BcatT);
    // M1: Pb = w1[:,512:]·[x2s|x]  (bf16)
    mfma_gemm<1, 1536><<<dim3(832), 256, 0, stream>>>(w1pT, BcatT, nullptr, sA, sB0, Pb);
    // M2: out = relu(bn(w1y[b]·yT + up(Pb)))  (49 tiles: 7,6x7 -> grid 8*8*7 per batch)
    mfma_gemm<2, 512><<<dim3(448, 1, B), 256, 0, stream>>>(w1y, yT, Pb, sA, sB1, out);
}

// Round 10
// 274.082 us; speedup vs baseline: 1.2842x; 1.0391x over previous
//
#include <hip/hip_runtime.h>
#include <math.h>

#define EPSV 1e-5f
#define B 8
#define C 1024
#define C2 512
#define RK 73
#define HW 784      // 28*28
#define QW 3136     // 56*56

typedef __attribute__((ext_vector_type(8))) short bf16x8;
typedef __attribute__((ext_vector_type(4))) float f32x4;

__device__ __forceinline__ unsigned short f2bf(float f) {
    unsigned u = __float_as_uint(f);
    return (unsigned short)((u + 0x7fffu + ((u >> 16) & 1u)) >> 16);
}
__device__ __forceinline__ float ld_f(const float* p) { return *p; }
__device__ __forceinline__ float ld_f(const unsigned short* p) {
    return __uint_as_float(((unsigned)*p) << 16);
}
// 4-wide load -> 4 floats (float4 for f32 src, uint2 of bf16 for ushort src)
__device__ __forceinline__ void ld4f(const float* p, float* d) {
    float4 v = *(const float4*)p;
    d[0] = v.x; d[1] = v.y; d[2] = v.z; d[3] = v.w;
}
__device__ __forceinline__ void ld4f(const unsigned short* p, float* d) {
    uint2 u = *(const uint2*)p;
    d[0] = __uint_as_float((u.x & 0xffffu) << 16);
    d[1] = __uint_as_float(u.x & 0xffff0000u);
    d[2] = __uint_as_float((u.y & 0xffffu) << 16);
    d[3] = __uint_as_float(u.y & 0xffff0000u);
}

// ---------- zero s0 before yT's atomic accumulation ----------
__global__ void zero_s0(float* __restrict__ s0) {
    s0[blockIdx.x * 256 + threadIdx.x] = 0.f;
}

// ---------- SE FC layers (s0 holds raw sums; scale by 1/QW here) ----------
__global__ void se_fc_kernel(const float* __restrict__ s0,
                             const float* __restrict__ fc1_w,
                             const float* __restrict__ fc2_w,
                             float* __restrict__ att) {
    int b = blockIdx.x;
    __shared__ float sv[C2];
    __shared__ float hv[RK];
    for (int i = threadIdx.x; i < C2; i += 256) sv[i] = s0[b * C2 + i] * (1.0f / QW);
    __syncthreads();
    if (threadIdx.x < RK) {
        float acc = 0.f;
        const float4* wr4 = (const float4*)(fc1_w + threadIdx.x * C2);
        const float4* sv4 = (const float4*)sv;
#pragma unroll 16
        for (int k = 0; k < C2 / 4; ++k) {
            float4 w4 = wr4[k], s4 = sv4[k];
            acc += w4.x * s4.x + w4.y * s4.y + w4.z * s4.z + w4.w * s4.w;
        }
        hv[threadIdx.x] = fmaxf(acc, 0.f);
    }
    __syncthreads();
    for (int o = threadIdx.x; o < C2; o += 256) {
        float acc = 0.f;
        const float* wr = fc2_w + o * RK;
#pragma unroll
        for (int j = 0; j < RK; ++j) acc += wr[j] * hv[j];
        att[b * C2 + o] = 1.f / (1.f + expf(-acc));
    }
}

// ---------- depthwise 3x3 conv + row-centered cov -> bf16 (2 channels/block) ----------
// cov[h][g] == cov[g][h] BITWISE -> compute 406 lower-triangle pairs, mirror-store.
// 2 channels per block (4096 blocks, was 8192): halves per-block fixed cost (barriers,
// rm pass, launch). Per-channel math unrolled with COMPILE-TIME ch -> bitwise identical.
__global__ void dwcov_kernel(const float* __restrict__ x,
                             const float* __restrict__ dw_w,
                             const float* __restrict__ dw_b,
                             unsigned short* __restrict__ cov) {
    int bc = blockIdx.x;                 // 0..4095
    int b = bc >> 9, c0 = (bc & 511) << 1;
    __shared__ __align__(16) float xs[2 * HW];
    __shared__ __align__(16) float x1[2 * HW];
    __shared__ float rm[2][28];
    int tid = threadIdx.x;
    const float* px = x + ((size_t)b * C + c0) * HW;   // 1568 floats, 16B-aligned
#pragma unroll
    for (int i4 = 0; i4 < 2; ++i4) {
        int e = tid + i4 * 256;
        if (e < 392) *(float4*)&xs[e * 4] = *(const float4*)&px[e * 4];
    }
    float wk0[9], wk1[9];
#pragma unroll
    for (int j = 0; j < 9; ++j) { wk0[j] = dw_w[c0 * 9 + j]; wk1[j] = dw_w[c0 * 9 + 9 + j]; }
    float bi0 = dw_b[c0], bi1 = dw_b[c0 + 1];
    __syncthreads();
#pragma unroll
    for (int ch = 0; ch < 2; ++ch) {
        const float* xsc = &xs[ch * HW];
        float* x1c = &x1[ch * HW];
        float bias = ch ? bi1 : bi0;
        for (int p = tid; p < HW; p += 256) {
            int h = p / 28, w = p - h * 28;
            float acc = bias;
#pragma unroll
            for (int dh = 0; dh < 3; ++dh) {
                int hh = h + dh - 1;
                if (hh < 0 || hh >= 28) continue;
#pragma unroll
                for (int dw = 0; dw < 3; ++dw) {
                    int ww = w + dw - 1;
                    if (ww < 0 || ww >= 28) continue;
                    acc += xsc[hh * 28 + ww] * (ch ? wk1[dh * 3 + dw] : wk0[dh * 3 + dw]);
                }
            }
            x1c[p] = acc;
        }
    }
    __syncthreads();
    if (tid < 56) {
        int ch = tid >= 28 ? 1 : 0, hh = tid - 28 * ch;
        const float* x1c = &x1[ch * HW];
        float s = 0.f;
        for (int w = 0; w < 28; ++w) s += x1c[hh * 28 + w];
        rm[ch][hh] = s * (1.f / 28.f);
    }
    __syncthreads();
#pragma unroll
    for (int ch = 0; ch < 2; ++ch) {
        unsigned short* pc = cov + ((size_t)b * C + c0 + ch) * HW;
        const float* x1c = &x1[ch * HW];
        for (int idx = tid; idx < 406; idx += 256) {     // 406 = 28*29/2
            int h = (int)((sqrtf((float)(8 * idx + 1)) - 1.f) * 0.5f);
            while ((h + 1) * (h + 2) / 2 <= idx) ++h;
            while (h * (h + 1) / 2 > idx) --h;
            int g = idx - h * (h + 1) / 2;               // g <= h
            float mh = rm[ch][h], mg = rm[ch][g];
            const float4* xh = (const float4*)&x1c[h * 28];
            const float4* xg = (const float4*)&x1c[g * 28];
            float acc = 0.f;
#pragma unroll
            for (int w4 = 0; w4 < 7; ++w4) {
                float4 a = xh[w4], bq = xg[w4];
                acc += (a.x - mh) * (bq.x - mg);
                acc += (a.y - mh) * (bq.y - mg);
                acc += (a.z - mh) * (bq.z - mg);
                acc += (a.w - mh) * (bq.w - mg);
            }
            unsigned short v = f2bf(acc * (1.f / 27.f));
            pc[h * 28 + g] = v;
            pc[g * 28 + h] = v;
        }
    }
}

// ---------- pack weights bf16; fold att into per-batch w1y; fold bias+bn ----------
__global__ void pack_w(const float* __restrict__ conv_w, const float* __restrict__ conv_b,
                       const float* __restrict__ conv1_w, const float* __restrict__ conv1_b,
                       const float* __restrict__ bn_g, const float* __restrict__ bn_b,
                       const float* __restrict__ bn_m, const float* __restrict__ bn_v,
                       const float* __restrict__ att,
                       unsigned short* __restrict__ w0b, unsigned short* __restrict__ w1y,
                       unsigned short* __restrict__ w1pT,
                       float* __restrict__ sA, float* __restrict__ sB0, float* __restrict__ sB1) {
    int o = blockIdx.x, t = threadIdx.x;
    // w0b: 1024 elems = 256 threads x float4
    {
        int c4 = t * 4;
        float4 w4 = *(const float4*)&conv_w[(size_t)o * C + c4];
        unsigned short pk[4] = { f2bf(w4.x), f2bf(w4.y), f2bf(w4.z), f2bf(w4.w) };
        *(uint2*)&w0b[(size_t)o * C + c4] = *(uint2*)pk;
    }
    // w1pT: 1536 elems = 384 float4 over 256 threads
#pragma unroll
    for (int i = 0; i < 2; ++i) {
        int e = t + i * 256;
        if (e < 384) {
            int c4 = e * 4;
            float4 w4 = *(const float4*)&conv1_w[(size_t)o * 2048 + 512 + c4];
            unsigned short pk[4] = { f2bf(w4.x), f2bf(w4.y), f2bf(w4.z), f2bf(w4.w) };
            *(uint2*)&w1pT[(size_t)o * 1536 + c4] = *(uint2*)pk;
        }
    }
    // w1y: B*C2 = 4096 elems = 1024 float4 over 256 threads
#pragma unroll
    for (int i = 0; i < 4; ++i) {
        int e = t + i * 256;
        int bb = e >> 7, c4 = (e & 127) * 4;
        float4 w4 = *(const float4*)&conv1_w[(size_t)o * 2048 + c4];
        float4 a4 = *(const float4*)&att[bb * C2 + c4];
        unsigned short pk[4] = { f2bf(w4.x * a4.x), f2bf(w4.y * a4.y),
                                 f2bf(w4.z * a4.z), f2bf(w4.w * a4.w) };
        *(uint2*)&w1y[((size_t)bb * C2 + o) * C2 + c4] = *(uint2*)pk;
    }
    if (t == 0) {
        float sc = rsqrtf(bn_v[o] + EPSV) * bn_g[o];
        float bi = bn_b[o] - bn_m[o] * sc;
        sA[o] = sc;
        sB0[o] = conv_b[o] * sc + bi;
        sB1[o] = conv1_b[o] * sc + bi;
    }
}

// ---------- tiled transpose+convert: src[b][rows][cols] -> dst[(b,col)][dpitch]+doff ----------
// Loads vectorized (float4 / uint2-bf16x4); stores two short8 (16B) per thread.
// GAP: additionally reduce each channel-row's 64 staged values and atomicAdd into
// s0[b*rows + c] (fuses the old gap_kernel's 51.4MB y re-read into this pass).
template<typename ST, bool GAP>
__global__ __launch_bounds__(256)
void transpose_pass(const ST* __restrict__ src, unsigned short* __restrict__ dst,
                    float* __restrict__ s0,
                    int rows, int cols, int dpitch, int doff) {
    int b = blockIdx.z;
    int c0 = blockIdx.y * 64, p0 = blockIdx.x * 64;
    __shared__ float ts[64][65];
    int tid = threadIdx.x;
    int pl4 = (tid & 15) * 4, rr = tid >> 4;
    const ST* sb = src + ((size_t)b * rows + c0) * cols + p0;
    if (p0 + pl4 < cols) {           // cols%4==0 -> full 4-vector valid
#pragma unroll
        for (int j = 0; j < 4; ++j) {
            int cl = rr + j * 16;
            float d[4];
            ld4f(&sb[(size_t)cl * cols + pl4], d);
            ts[cl][pl4 + 0] = d[0]; ts[cl][pl4 + 1] = d[1];
            ts[cl][pl4 + 2] = d[2]; ts[cl][pl4 + 3] = d[3];
        }
    }
    __syncthreads();
    int pl2b = tid >> 3, cl0 = (tid & 7) * 8;
#pragma unroll
    for (int j = 0; j < 2; ++j) {
        int pl2 = pl2b + j * 32;
        if (p0 + pl2 < cols) {
            unsigned short pk[8];
#pragma unroll
            for (int i = 0; i < 8; ++i) pk[i] = f2bf(ts[cl0 + i][pl2]);
            *(uint4*)&dst[((size_t)b * cols + p0 + pl2) * dpitch + doff + c0 + cl0] = *(uint4*)pk;
        }
    }
    if (GAP) {
        if (tid < 64) {
            float s = 0.f;
#pragma unroll
            for (int i = 0; i < 64; ++i) s += ts[tid][i];   // banks (tid*65+i)%32 distinct per tid
            atomicAdd(&s0[b * rows + c0 + tid], s);
        }
    }
}

// ---------- MFMA GEMM: 64o x 64n, BK=64 bodies, 4-deep reg prefetch ----------
// LDS rows 128B; swizzle by ROW: 16B chunk c (0..7) of row r at r*64 + 8*(c^(r&7))
// shorts, same XOR on read (R5/R7-verified conflict-free).
// Pipeline: 4 register stage-sets, lead = 4 bodies (~1600cy >> 900cy HBM latency);
// loads stay in flight across raw s_barrier (lgkmcnt-only publish, no vmcnt(0)).
// XCD classes balanced & bijective; XCD = bx%8 (grid.x%8==0 under blockIdx.z).
// MODE 0: A=w0b K=1024, B=cov_bf STRIDED [(b,k)][p] -- NO covT pass. z=batch, N=784,
//   13 tiles (tail masked). Thread (n0=2*(tid&31), kg=tid>>5) loads 8 uints (2 bf16,
//   stride HW, coalesced 128B per 32 lanes); lo/hi repack DEFERRED to ds_write (keeps
//   4-body vmcnt lead); two swizzled b128 writes (2-way conflict = free, m136).
//   Epi bn+sigmoid -> BcatT[(b*HW+p)][0..511], p-guarded.
// MODE 1: A=w1pT   K=1536, B=BcatT [(b,p)][1536]; epi f2bf -> Pb [b][o][784]
// MODE 2: A=w1y[b] K=512,  B=yT    [(b,q)][512];  epi (acc+up(Pb))*bn relu -> out
template<int MODE, int K>
__global__ __launch_bounds__(256)
void mfma_gemm(const unsigned short* __restrict__ wpk,
               const unsigned short* __restrict__ bsrc,
               const unsigned short* __restrict__ Pb,
               const float* __restrict__ sA, const float* __restrict__ sB,
               void* __restrict__ outv) {
    constexpr int NIT = K / 64;                  // 16 / 24 / 8 -- all %4==0
    constexpr int NT  = (MODE == 1) ? 98 : ((MODE == 0) ? 13 : 49);
    constexpr int QN = NT >> 3, REM = NT & 7;
    int bx = blockIdx.x;
    int r = bx & 7, ii = bx >> 3;
    int og = ii & 7, s = ii >> 3;
    int cnt = QN + (r < REM ? 1 : 0);
    if (s >= cnt) return;
    int t = (r < REM ? r * (QN + 1) : REM * (QN + 1) + (r - REM) * QN) + s;
    int o0 = og * 64;
    int n0 = t * 64;
    int b = blockIdx.z;
    union SM {
        struct { __align__(16) unsigned short Wt[2][4096]; __align__(16) unsigned short At[2][4096]; } s;
        float pt[(MODE == 2) ? 64 * 84 : 4];
    };
    __shared__ SM sm;
    int tid = threadIdx.x;
    int lane = tid & 63, wv = tid >> 6;
    int ln = lane & 15, quad = lane >> 4;
    int o_w = (wv >> 1) * 32, q_w = (wv & 1) * 32;
    int r_ = tid >> 2, cq = tid & 3;             // A staging: row, 32B column pair
    int stw0 = r_ * 64 + ((( cq << 1)      ^ (r_ & 7)) << 3);   // swizzled write offs
    int stw1 = r_ * 64 + ((((cq << 1) | 1) ^ (r_ & 7)) << 3);
    int rq0 = (( quad      ^ (ln & 7)) << 3);    // swizzled read chunk, kk=0
    int rq1 = (((4 | quad) ^ (ln & 7)) << 3);    // kk=1
    const unsigned short* wp = (MODE == 2) ? wpk + (size_t)b * C2 * C2 : wpk;
    const unsigned short* wg = wp + (size_t)(o0 + r_) * K + cq * 16;
    // B pointers / staging mapping
    const unsigned short* bg = nullptr;          // MODE1/2 contiguous
    const unsigned short* bgs = nullptr;         // MODE0 strided base
    int n0l = 0, kg = 0, bw0 = 0, bw1 = 0;
    if (MODE == 0) {
        n0l = (tid & 31) * 2;
        kg = tid >> 5;
        int pg = min(n0 + n0l, HW - 2);          // clamp keeps uint load in-row (dead lanes)
        bgs = bsrc + ((size_t)b * C + kg * 8) * HW + pg;
        bw0 = n0l * 64 + ((kg ^ (n0l & 7)) << 3);
        bw1 = (n0l + 1) * 64 + ((kg ^ ((n0l + 1) & 7)) << 3);
    } else {
        bg = bsrc + ((size_t)((MODE == 2) ? b * QW : 0) + n0 + r_) * K + cq * 16;
    }

    uint4 stA_a0, stA_a1, stA_b0, stA_b1;        // 4 register stage-sets
    uint4 stB_a0, stB_a1, stB_b0, stB_b1;
    uint4 stC_a0, stC_a1, stC_b0, stC_b1;
    uint4 stD_a0, stD_a1, stD_b0, stD_b1;
    unsigned stA_u[8], stB_u[8], stC_u[8], stD_u[8];   // MODE0 raw strided B

#define LD_STAGE(P, CH) {                                                   \
        P##_a0 = *(const uint4*)(wg + (size_t)(CH) * 64);                   \
        P##_a1 = *(const uint4*)(wg + (size_t)(CH) * 64 + 8);               \
        if (MODE == 0) {                                                    \
            _Pragma("unroll")                                               \
            for (int _j = 0; _j < 8; ++_j)                                  \
                P##_u[_j] = *(const unsigned*)(bgs + (size_t)((CH) * 64 + _j) * HW); \
        } else {                                                            \
            P##_b0 = *(const uint4*)(bg + (size_t)(CH) * 64);               \
            P##_b1 = *(const uint4*)(bg + (size_t)(CH) * 64 + 8);           \
        } }

#define ST_STAGE(P, BUF) {                                                  \
        *(uint4*)&sm.s.Wt[BUF][stw0] = P##_a0;                              \
        *(uint4*)&sm.s.Wt[BUF][stw1] = P##_a1;                              \
        if (MODE == 0) {                                                    \
            uint4 _lo, _hi;                                                 \
            _lo.x = (P##_u[0] & 0xffffu) | (P##_u[1] << 16);                \
            _lo.y = (P##_u[2] & 0xffffu) | (P##_u[3] << 16);                \
            _lo.z = (P##_u[4] & 0xffffu) | (P##_u[5] << 16);                \
            _lo.w = (P##_u[6] & 0xffffu) | (P##_u[7] << 16);                \
            _hi.x = (P##_u[0] >> 16) | (P##_u[1] & 0xffff0000u);            \
            _hi.y = (P##_u[2] >> 16) | (P##_u[3] & 0xffff0000u);            \
            _hi.z = (P##_u[4] >> 16) | (P##_u[5] & 0xffff0000u);            \
            _hi.w = (P##_u[6] >> 16) | (P##_u[7] & 0xffff0000u);            \
            *(uint4*)&sm.s.At[BUF][bw0] = _lo;                              \
            *(uint4*)&sm.s.At[BUF][bw1] = _hi;                              \
        } else {                                                            \
            *(uint4*)&sm.s.At[BUF][stw0] = P##_b0;                          \
            *(uint4*)&sm.s.At[BUF][stw1] = P##_b1;                          \
        } }

#define GEMM_BODY(BUF, P, CHW, CHL) {                                               \
        bf16x8 a0 = *(const bf16x8*)&sm.s.Wt[BUF][(o_w + ln) * 64 + rq0];           \
        bf16x8 a1 = *(const bf16x8*)&sm.s.Wt[BUF][(o_w + 16 + ln) * 64 + rq0];      \
        bf16x8 b0 = *(const bf16x8*)&sm.s.At[BUF][(q_w + ln) * 64 + rq0];           \
        bf16x8 b1 = *(const bf16x8*)&sm.s.At[BUF][(q_w + 16 + ln) * 64 + rq0];      \
        bf16x8 a2 = *(const bf16x8*)&sm.s.Wt[BUF][(o_w + ln) * 64 + rq1];           \
        bf16x8 a3 = *(const bf16x8*)&sm.s.Wt[BUF][(o_w + 16 + ln) * 64 + rq1];      \
        bf16x8 b2 = *(const bf16x8*)&sm.s.At[BUF][(q_w + ln) * 64 + rq1];           \
        bf16x8 b3 = *(const bf16x8*)&sm.s.At[BUF][(q_w + 16 + ln) * 64 + rq1];      \
        acc[0][0] = __builtin_amdgcn_mfma_f32_16x16x32_bf16(a0, b0, acc[0][0], 0, 0, 0); \
        acc[0][1] = __builtin_amdgcn_mfma_f32_16x16x32_bf16(a0, b1, acc[0][1], 0, 0, 0); \
        acc[1][0] = __builtin_amdgcn_mfma_f32_16x16x32_bf16(a1, b0, acc[1][0], 0, 0, 0); \
        acc[1][1] = __builtin_amdgcn_mfma_f32_16x16x32_bf16(a1, b1, acc[1][1], 0, 0, 0); \
        acc[0][0] = __builtin_amdgcn_mfma_f32_16x16x32_bf16(a2, b2, acc[0][0], 0, 0, 0); \
        acc[0][1] = __builtin_amdgcn_mfma_f32_16x16x32_bf16(a2, b3, acc[0][1], 0, 0, 0); \
        acc[1][0] = __builtin_amdgcn_mfma_f32_16x16x32_bf16(a3, b2, acc[1][0], 0, 0, 0); \
        acc[1][1] = __builtin_amdgcn_mfma_f32_16x16x32_bf16(a3, b3, acc[1][1], 0, 0, 0); \
        if ((CHW) < NIT) {                                                          \
            ST_STAGE(P, (BUF) ^ 1)                                                  \
            if ((CHL) < NIT) LD_STAGE(P, (CHL))                                     \
            asm volatile("s_waitcnt lgkmcnt(0)" ::: "memory");                      \
            __builtin_amdgcn_s_barrier();                                           \
            __builtin_amdgcn_sched_barrier(0);                                      \
        } }

    // prologue: chunk0 -> LDS[0]; chunks 1..4 in flight across the barrier
    LD_STAGE(stA, 0)
    ST_STAGE(stA, 0)
    LD_STAGE(stB, 1)
    LD_STAGE(stC, 2)
    LD_STAGE(stD, 3)
    LD_STAGE(stA, 4)
    asm volatile("s_waitcnt lgkmcnt(0)" ::: "memory");
    __builtin_amdgcn_s_barrier();
    __builtin_amdgcn_sched_barrier(0);

    f32x4 acc[2][2] = {};
    for (int i2 = 0; i2 < NIT; i2 += 4) {
        GEMM_BODY(0, stB, i2 + 1, i2 + 5)
        GEMM_BODY(1, stC, i2 + 2, i2 + 6)
        GEMM_BODY(0, stD, i2 + 3, i2 + 7)
        GEMM_BODY(1, stA, i2 + 4, i2 + 8)
    }
#undef GEMM_BODY
#undef ST_STAGE
#undef LD_STAGE

    // ---- epilogue; D: row = quad*4+reg, col = ln ----
    if (MODE == 2) {
        float* outp = (float*)outv;
        int h0 = n0 / 56;
        int hmin = (h0 & 1) ? (h0 >> 1) : max(0, (h0 >> 1) - 1);
        // batched Pb staging: 21 independent loads in flight, then publish to LDS.
        float stv[21];
#pragma unroll
        for (int j = 0; j < 21; ++j) {
            int e = tid + j * 256;               // 21*256 == 64*84 exactly
            int o_l = e / 84, rem = e - o_l * 84;
            int s2 = rem / 28, w = rem - s2 * 28;
            int row = min(hmin + s2, 27);
            stv[j] = ld_f(&Pb[((size_t)b * C2 + o0 + o_l) * HW + row * 28 + w]);
        }
        __syncthreads();                          // all waves done with K-loop LDS
#pragma unroll
        for (int j = 0; j < 21; ++j) sm.pt[tid + j * 256] = stv[j];
        __syncthreads();
#pragma unroll
        for (int nt = 0; nt < 2; ++nt) {
            int q = n0 + q_w + nt * 16 + ln;
            int hq = q / 56, wq = q - hq * 56;
            int hm = hq >> 1, wm = wq >> 1;
            int hn = (hq & 1) ? min(hm + 1, 27) : max(hm - 1, 0);
            int wn_ = (wq & 1) ? min(wm + 1, 27) : max(wm - 1, 0);
            int rm_ = (hm - hmin) * 28, rn_ = (hn - hmin) * 28;
#pragma unroll
            for (int mt = 0; mt < 2; ++mt)
#pragma unroll
                for (int reg = 0; reg < 4; ++reg) {
                    int ol = o_w + mt * 16 + quad * 4 + reg;
                    int o = o0 + ol;
                    const float* Pt = &sm.pt[ol * 84];
                    float up = 0.5625f * Pt[rm_ + wm] + 0.1875f * (Pt[rm_ + wn_] + Pt[rn_ + wm])
                             + 0.0625f * Pt[rn_ + wn_];
                    float v = (acc[mt][nt][reg] + up) * sA[o] + sB[o];
                    outp[((size_t)b * C2 + o) * QW + q] = fmaxf(v, 0.f);
                }
        }
    } else if (MODE == 0) {
        unsigned short* outp = (unsigned short*)outv;   // BcatT, pitch 1536, cols 0..511
#pragma unroll
        for (int nt = 0; nt < 2; ++nt) {
            int p = n0 + q_w + nt * 16 + ln;
            if (p < HW) {
                size_t n = (size_t)b * HW + p;
#pragma unroll
                for (int mt = 0; mt < 2; ++mt) {
                    int ob = o0 + o_w + mt * 16 + quad * 4;
                    unsigned short pk[4];
#pragma unroll
                    for (int reg = 0; reg < 4; ++reg) {
                        int o = ob + reg;
                        float v = acc[mt][nt][reg] * sA[o] + sB[o];
                        pk[reg] = f2bf(1.f / (1.f + expf(-v)));
                    }
                    *(uint2*)&outp[n * 1536 + ob] = *(uint2*)pk;
                }
            }
        }
    } else {
        unsigned short* outp = (unsigned short*)outv;   // Pb [b][o][784] bf16
#pragma unroll
        for (int nt = 0; nt < 2; ++nt) {
            int n = n0 + q_w + nt * 16 + ln;
            int be = n / HW, pe = n - be * HW;
#pragma unroll
            for (int mt = 0; mt < 2; ++mt)
#pragma unroll
                for (int reg = 0; reg < 4; ++reg) {
                    int o = o0 + o_w + mt * 16 + quad * 4 + reg;
                    outp[((size_t)be * C2 + o) * HW + pe] = f2bf(acc[mt][nt][reg]);
                }
        }
    }
}

extern "C" void kernel_launch(void* const* d_in, const int* in_sizes, int n_in,
                              void* d_out, int out_size, void* d_ws, size_t ws_size,
                              hipStream_t stream) {
    const float* y       = (const float*)d_in[0];
    const float* x       = (const float*)d_in[1];
    const float* fc1_w   = (const float*)d_in[2];
    const float* fc2_w   = (const float*)d_in[3];
    const float* conv_w  = (const float*)d_in[4];
    const float* conv_b  = (const float*)d_in[5];
    const float* conv1_w = (const float*)d_in[6];
    const float* conv1_b = (const float*)d_in[7];
    const float* bn_g    = (const float*)d_in[8];
    const float* bn_b    = (const float*)d_in[9];
    const float* bn_m    = (const float*)d_in[10];
    const float* bn_v    = (const float*)d_in[11];
    const float* dw_w    = (const float*)d_in[12];
    const float* dw_b    = (const float*)d_in[13];
    float* out = (float*)d_out;

    // ---- d_out doubles as scratch for buffers that die before M2's epilogue ----
    // cov_bf(12.85M) + BcatT(19.27M) = 32,112,640 B <= out 51,380,224 B. (covT is GONE:
    // M0 reads cov_bf strided.) M2 fully overwrites out; M1 (reads BcatT) completes first.
    unsigned short* cov_bf = (unsigned short*)d_out;         // 8*1024*784
    unsigned short* BcatT  = cov_bf + (size_t)B * C * HW;    // 6272*1536

    // ---- ws carve: 39,491,584 B (< Round-2-proven 45,389,824 extent) ----
    float* ws  = (float*)d_ws;
    float* s0  = ws;                 // 4096
    float* att = ws + 4096;          // 4096
    float* sA  = ws + 8192;          // 512
    float* sB0 = ws + 8704;          // 512
    float* sB1 = ws + 9216;          // 512 -> header ends at float 9728 (byte 38912, 16B-aligned)
    unsigned short* w0b  = (unsigned short*)(ws + 9728);     // 512*1024 sh
    unsigned short* w1y  = w0b + (size_t)C2 * C;             // 8*512*512 sh
    unsigned short* w1pT = w1y + (size_t)B * C2 * C2;        // 512*1536 sh
    unsigned short* yT   = w1pT + (size_t)C2 * 1536;         // 8*3136*512 sh
    unsigned short* Pb   = yT + (size_t)B * QW * C2;         // 8*512*784 sh

    // gap fused into yT: zero s0, transpose y (read ONCE) with atomic channel sums
    zero_s0<<<16, 256, 0, stream>>>(s0);
    transpose_pass<float, true><<<dim3(49, 8, B), 256, 0, stream>>>(
        y, yT, s0, C2, QW, C2, 0);
    se_fc_kernel<<<B, 256, 0, stream>>>(s0, fc1_w, fc2_w, att);
    pack_w<<<C2, 256, 0, stream>>>(conv_w, conv_b, conv1_w, conv1_b,
                                   bn_g, bn_b, bn_m, bn_v, att,
                                   w0b, w1y, w1pT, sA, sB0, sB1);
    dwcov_kernel<<<B * C / 2, 256, 0, stream>>>(x, dw_w, dw_b, cov_bf);
    // xT: x[b][c][p] -> BcatT[(b,p)][512+c]
    transpose_pass<float, false><<<dim3(13, 16, B), 256, 0, stream>>>(
        x, BcatT, nullptr, C, HW, 1536, 512);
    // M0: x2s = sigmoid(bn(conv(cov))) -> BcatT cols 0..511
    //     z-batched, B strided from cov_bf (13 tiles: classes 2,2,2,2,2,1,1,1 -> grid 8*8*2)
    mfma_gemm<0, 1024><<<dim3(128, 1, B), 256, 0, stream>>>(w0b, cov_bf, nullptr, sA, sB0, BcatT);
    // M1: Pb = w1[:,512:]·[x2s|x]  (bf16)  (98 tiles: 13,13,12x6 -> grid 8*8*13)
    mfma_gemm<1, 1536><<<dim3(832), 256, 0, stream>>>(w1pT, BcatT, nullptr, sA, sB0, Pb);
    // M2: out = relu(bn(w1y[b]·yT + up(Pb)))  (49 tiles: 7,6x7 -> grid 8*8*7 per batch)
    mfma_gemm<2, 512><<<dim3(448, 1, B), 256, 0, stream>>>(w1y, yT, Pb, sA, sB1, out);
}